// Round 5
// baseline (1458.718 us; speedup 1.0000x reference)
//
#include <hip/hip_runtime.h>
#include <hip/hip_bf16.h>
#include <math.h>

typedef short bf16x8 __attribute__((ext_vector_type(8)));
typedef float f32x16 __attribute__((ext_vector_type(16)));

#define DH 100      // hidden dim
#define SPB 20      // samples per block -> 2020 rows, padded to 2048
#define NCH 16      // chunks of 128 rows
#define WSTR 136    // LDS row stride in bf16 elems (272 B => conflict-free b128)

// ws float offsets
#define WS_CCW   0
#define WS_XSC   128
#define WS_OH0   256
#define WS_EOH1  260
#define WS_X2    272

__device__ __forceinline__ unsigned short f2bf(float f) {
    unsigned int u = __float_as_uint(f);
    unsigned int r = (u + 0x7FFFu + ((u >> 16) & 1u)) >> 16;  // RNE
    return (unsigned short)r;
}
__device__ __forceinline__ unsigned int pk2(float a, float b) {
    // packed f32->bf16 (v_cvt_pk_bf16_f32); low u16 = a
    __hip_bfloat162 h = __float22bfloat162_rn(make_float2(a, b));
    union { __hip_bfloat162 h; unsigned int u; } c; c.h = h; return c.u;
}

__global__ void setup_kernel(const float* __restrict__ logits,
                             const float* __restrict__ hb0,
                             const float* __restrict__ hW1,
                             const float* __restrict__ hb1,
                             const float* __restrict__ hW2,
                             const float* __restrict__ hb2,
                             const float* __restrict__ hW3,
                             const float* __restrict__ hb3,
                             float* __restrict__ ws,
                             float* __restrict__ out2, int n)
{
    int t = threadIdx.x;
    for (int i = blockIdx.x * blockDim.x + t; i < n; i += gridDim.x * blockDim.x)
        out2[i] = logits[i];
    if (blockIdx.x != 0) return;

    if (t < 128) {
        double ccw = 0.0, xs = 0.0;
        if (t <= 100) {
            double s = (double)t;
            for (int j = 0; j <= 100; j += 2) {
                double wj = (j == 0) ? 1.0 : 2.0 / (1.0 - (double)j * (double)j);
                double lam;
                if (t == 0) lam = 0.5;
                else {
                    lam = cos((double)j * s * M_PI / 100.0);
                    if (t == 100) lam *= 0.5;
                }
                ccw += lam * 0.02 * wj;
            }
            xs = (cos(s * M_PI / 100.0) + 1.0) * 0.5;
        }
        ws[WS_CCW + t] = (float)ccw;
        ws[WS_XSC + t] = (float)xs;
    }
    __syncthreads();

    __shared__ float bufA[DH], bufB[DH];
    for (int k = 0; k < 3; ++k) {
        if (t < DH) bufA[t] = fmaxf(hb0[k * DH + t], 0.f);
        __syncthreads();
        if (t < DH) {
            float acc = hb1[k * DH + t];
            const float* w = hW1 + (size_t)(k * DH + t) * DH;
            for (int i = 0; i < DH; ++i) acc = fmaf(w[i], bufA[i], acc);
            bufB[t] = fmaxf(acc, 0.f);
        }
        __syncthreads();
        if (t < DH) {
            float acc = hb2[k * DH + t];
            const float* w = hW2 + (size_t)(k * DH + t) * DH;
            for (int i = 0; i < DH; ++i) acc = fmaf(w[i], bufB[i], acc);
            bufA[t] = fmaxf(acc, 0.f);
        }
        __syncthreads();
        if (t < 2) {
            float acc = hb3[k * 2 + t];
            const float* w = hW3 + (size_t)(k * 2 + t) * DH;
            for (int i = 0; i < DH; ++i) acc = fmaf(w[i], bufA[i], acc);
            if (t == 0) ws[WS_OH0 + k] = acc;
            else        ws[WS_EOH1 + k] = expf(acc);
        }
        __syncthreads();
    }
}

// Transposed dataflow (verified R3/R4): C1 = W1·A1^T, C2 = W2·A2^T; inter-layer
// C->B-operand transform via lane^32 shuffle exchange. nt-outer single-tile
// loops keep peak live registers ~140 (no spill). Weight LDS holds only the
// 100 real rows; reads clamp to row 99 — garbage C-rows are killed downstream
// by zero W2 columns (>100) and zero w3 entries (>=100).
__global__ __launch_bounds__(256)
void mono_mfma(const float* __restrict__ xsrc,
               const float* __restrict__ iW0, const float* __restrict__ ib0,
               const float* __restrict__ iW1, const float* __restrict__ ib1,
               const float* __restrict__ iW2, const float* __restrict__ ib2,
               const float* __restrict__ iW3, const float* __restrict__ ib3,
               const float* __restrict__ ws,
               float* __restrict__ dst0, float* __restrict__ dst1,
               int kbase, int nTot)
{
    __shared__ __align__(16) unsigned short W1s[DH * WSTR];  // row n1<100, col kin; col 100 = b1
    __shared__ __align__(16) unsigned short W2s[DH * WSTR];  // row n2<100, col n1;  col 100 = b2
    __shared__ unsigned int wb_s[128];    // packed (bf16(b0)<<16)|bf16(w0); slot 100 = (1.0, 0)
    __shared__ unsigned int w3p_s[64];    // packed bf16 w3 pairs, [hf][nt2][q][pr]; 0 for n2>=100
    __shared__ float xsc_s[128], ccw_s[128];
    __shared__ float xs_s[32], zs[32];

    const int tid = threadIdx.x;
    const int lane = tid & 63;
    const int wv = tid >> 6;
    const int hf = lane >> 5;
    const bool hfb = (hf != 0);
    const int l31 = lane & 31;
    const int k = kbase + blockIdx.y;
    float* __restrict__ dst = (blockIdx.y == 0) ? dst0 : dst1;

    const float* W1g = iW1 + (size_t)k * DH * DH;
    const float* W2g = iW2 + (size_t)k * DH * DH;

    if (tid < 128) {
        xsc_s[tid] = ws[WS_XSC + tid];
        ccw_s[tid] = ws[WS_CCW + tid];
        float w0 = (tid < DH) ? iW0[(k * DH + tid) * 3] : 0.f;   // h==0: feature 0 only
        float b0 = (tid < DH) ? ib0[k * DH + tid] : ((tid == DH) ? 1.f : 0.f);
        wb_s[tid] = ((unsigned int)f2bf(b0) << 16) | (unsigned int)f2bf(w0);
    }
    if (tid < 64) {
        int hf_i = tid >> 5, rem = tid & 31;
        int nt2 = rem >> 3, qq = (rem >> 1) & 3, pr = rem & 1;
        int n2e = 32 * nt2 + 8 * qq + 2 * pr + 4 * hf_i;
        float we = (n2e < DH) ? iW3[k * DH + n2e] : 0.f;
        float wo = (n2e + 1 < DH) ? iW3[k * DH + n2e + 1] : 0.f;
        w3p_s[tid] = ((unsigned int)f2bf(wo) << 16) | (unsigned int)f2bf(we);
    }
    if (tid < 32) {
        int n = blockIdx.x * SPB + tid;
        xs_s[tid] = (tid < SPB && n < nTot) ? xsrc[n] : 0.f;
        zs[tid] = 0.f;
    }
    // stage W1/W2 (100 rows x 128 cols; col 100 = bias, 101..127 = 0)
    for (int i = tid; i < DH * 128; i += 256) {
        int r = i >> 7, c = i & 127;
        float v1, v2;
        if (c < DH)       { v1 = W1g[r * DH + c]; v2 = W2g[r * DH + c]; }
        else if (c == DH) { v1 = ib1[k * DH + r]; v2 = ib2[k * DH + r]; }
        else              { v1 = 0.f; v2 = 0.f; }
        W1s[r * WSTR + c] = f2bf(v1);
        W2s[r * WSTR + c] = f2bf(v2);
    }
    __syncthreads();

    const float b3 = ib3[k];
    const float e1 = ws[WS_EOH1 + k];
    const float o0 = ws[WS_OH0 + k];

    // per-lane weight-fragment LDS base offsets (row clamped to 99)
    int wrow[4];
    #pragma unroll
    for (int nt = 0; nt < 4; ++nt) {
        int r = nt * 32 + l31;
        wrow[nt] = ((r > DH - 1) ? (DH - 1) : r) * WSTR + hf * 8;
    }

    union FR { bf16x8 v; unsigned int u32[4]; };

    for (int ch = 0; ch < NCH; ++ch) {
        const int mrow = ch * 128 + wv * 32 + l31;
        const int nloc = (mrow * 649) >> 16;   // mrow / 101
        const int p = mrow - nloc * 101;
        const float u = xs_s[nloc] * xsc_s[p];

        // ---- layer 1: build all 8 B-frags (rank-1 in u; bias in slot 100) ----
        FR a1[8];
        #pragma unroll
        for (int ks = 0; ks < 8; ++ks) {
            const unsigned int* wb = &wb_s[ks * 16 + hf * 8];
            uint4 qa = *(const uint4*)wb;
            uint4 qb = *(const uint4*)(wb + 4);
            unsigned int q[8] = {qa.x, qa.y, qa.z, qa.w, qb.x, qb.y, qb.z, qb.w};
            float v[8];
            #pragma unroll
            for (int j = 0; j < 8; ++j) {
                float w0 = __uint_as_float(q[j] << 16);
                float b0 = __uint_as_float(q[j] & 0xFFFF0000u);
                v[j] = fmaxf(fmaf(u, w0, b0), 0.f);
            }
            a1[ks].u32[0] = pk2(v[0], v[1]);
            a1[ks].u32[1] = pk2(v[2], v[3]);
            a1[ks].u32[2] = pk2(v[4], v[5]);
            a1[ks].u32[3] = pk2(v[6], v[7]);
        }

        // ---- layer 2: nt-outer, one 16-reg accumulator; pack+exchange -> f3 ----
        FR f3[8];
        #pragma unroll
        for (int nt = 0; nt < 4; ++nt) {
            f32x16 acc;
            #pragma unroll
            for (int r = 0; r < 16; ++r) acc[r] = 0.f;
            #pragma unroll
            for (int ks = 0; ks < 8; ++ks) {
                bf16x8 wA = *(const bf16x8*)&W1s[wrow[nt] + ks * 16];
                acc = __builtin_amdgcn_mfma_f32_32x32x16_bf16(wA, a1[ks].v, acc, 0, 0, 0);
            }
            unsigned int pk[4][2];
            #pragma unroll
            for (int qi = 0; qi < 4; ++qi) {
                float a0 = fmaxf(acc[4 * qi + 0], 0.f);
                float a1v = fmaxf(acc[4 * qi + 1], 0.f);
                float a2 = fmaxf(acc[4 * qi + 2], 0.f);
                float a3 = fmaxf(acc[4 * qi + 3], 0.f);
                pk[qi][0] = pk2(a0, a1v);
                pk[qi][1] = pk2(a2, a3);
            }
            #pragma unroll
            for (int kk = 0; kk < 2; ++kk) {
                unsigned int X0 = hfb ? pk[2 * kk][0] : pk[2 * kk + 1][0];
                unsigned int X1 = hfb ? pk[2 * kk][1] : pk[2 * kk + 1][1];
                unsigned int O0 = hfb ? pk[2 * kk + 1][0] : pk[2 * kk][0];
                unsigned int O1 = hfb ? pk[2 * kk + 1][1] : pk[2 * kk][1];
                unsigned int Y0 = (unsigned int)__shfl_xor((int)X0, 32, 64);
                unsigned int Y1 = (unsigned int)__shfl_xor((int)X1, 32, 64);
                f3[nt * 2 + kk].u32[0] = hfb ? Y0 : O0;
                f3[nt * 2 + kk].u32[1] = hfb ? Y1 : O1;
                f3[nt * 2 + kk].u32[2] = hfb ? O0 : Y0;
                f3[nt * 2 + kk].u32[3] = hfb ? O1 : Y1;
            }
        }
        // bias slot n1=100 := 1.0 exactly (hf=0 low half of f3[6].u32[2]);
        // n1=101..127 garbage is killed by zero W2 columns.
        f3[6].u32[2] = hfb ? f3[6].u32[2]
                           : ((f3[6].u32[2] & 0xFFFF0000u) | 0x00003F80u);

        // ---- layer 3: nt2-outer, one accumulator; fold w3 (from LDS) ----
        float oacc = 0.f;
        #pragma unroll
        for (int nt2 = 0; nt2 < 4; ++nt2) {
            f32x16 acc2;
            #pragma unroll
            for (int r = 0; r < 16; ++r) acc2[r] = 0.f;
            #pragma unroll
            for (int ks = 0; ks < 8; ++ks) {
                bf16x8 wA = *(const bf16x8*)&W2s[wrow[nt2] + ks * 16];
                acc2 = __builtin_amdgcn_mfma_f32_32x32x16_bf16(wA, f3[ks].v, acc2, 0, 0, 0);
            }
            uint4 wa = *(const uint4*)&w3p_s[hf * 32 + nt2 * 8];
            uint4 wb2 = *(const uint4*)&w3p_s[hf * 32 + nt2 * 8 + 4];
            unsigned int w8[8] = {wa.x, wa.y, wa.z, wa.w, wb2.x, wb2.y, wb2.z, wb2.w};
            #pragma unroll
            for (int r = 0; r < 16; ++r) {
                int qi = r >> 2, s = r & 3;
                unsigned int wu = w8[qi * 2 + (s >> 1)];
                float w3v = __uint_as_float((s & 1) ? (wu & 0xFFFF0000u) : (wu << 16));
                oacc = fmaf(fmaxf(acc2[r], 0.f), w3v, oacc);
            }
        }

        float o = oacc + __shfl_xor(oacc, 32, 64) + b3;
        float dz = (o > 0.f) ? (o + 1.f) : expf(o);   // elu(o) + 1
        float val = dz * ccw_s[p];
        int nA = __shfl(nloc, 0, 32);
        int nB = __shfl(nloc, 31, 32);
        float vA = (nloc == nA) ? val : 0.f;
        vA += __shfl_xor(vA, 16, 32);
        vA += __shfl_xor(vA, 8, 32);
        vA += __shfl_xor(vA, 4, 32);
        vA += __shfl_xor(vA, 2, 32);
        vA += __shfl_xor(vA, 1, 32);
        if (lane == 0) atomicAdd(&zs[nA], vA);
        if (nB != nA) {
            float vB = (nloc == nB) ? val : 0.f;
            vB += __shfl_xor(vB, 16, 32);
            vB += __shfl_xor(vB, 8, 32);
            vB += __shfl_xor(vB, 4, 32);
            vB += __shfl_xor(vB, 2, 32);
            vB += __shfl_xor(vB, 1, 32);
            if (lane == 1) atomicAdd(&zs[nB], vB);
        }
    }

    __syncthreads();
    if (tid < SPB) {
        int n = blockIdx.x * SPB + tid;
        if (n < nTot) dst[n] = fmaf(e1, 0.5f * xs_s[tid] * zs[tid], o0);
    }
}

extern "C" void kernel_launch(void* const* d_in, const int* in_sizes, int n_in,
                              void* d_out, int out_size, void* d_ws, size_t ws_size,
                              hipStream_t stream)
{
    const float* logits = (const float*)d_in[0];
    const float* iW0 = (const float*)d_in[2];
    const float* ib0 = (const float*)d_in[3];
    const float* iW1 = (const float*)d_in[4];
    const float* ib1 = (const float*)d_in[5];
    const float* iW2 = (const float*)d_in[6];
    const float* ib2 = (const float*)d_in[7];
    const float* iW3 = (const float*)d_in[8];
    const float* ib3 = (const float*)d_in[9];
    const float* hb0 = (const float*)d_in[11];
    const float* hW1 = (const float*)d_in[12];
    const float* hb1 = (const float*)d_in[13];
    const float* hW2 = (const float*)d_in[14];
    const float* hb2 = (const float*)d_in[15];
    const float* hW3 = (const float*)d_in[16];
    const float* hb3 = (const float*)d_in[17];
    float* out = (float*)d_out;
    float* ws = (float*)d_ws;
    int n = in_sizes[0];
    int nblocks = (n + SPB - 1) / SPB;

    hipLaunchKernelGGL(setup_kernel, dim3(64), dim3(256), 0, stream,
                       logits, hb0, hW1, hb1, hW2, hb2, hW3, hb3, ws, out + 2 * n, n);
    // phase A: k=0 -> x2 (workspace), k=1 -> y1
    hipLaunchKernelGGL(mono_mfma, dim3(nblocks, 2), dim3(256), 0, stream,
                       logits, iW0, ib0, iW1, ib1, iW2, ib2, iW3, ib3, ws,
                       ws + WS_X2, out, 0, n);
    // phase B: k=2 on x2 -> y2
    hipLaunchKernelGGL(mono_mfma, dim3(nblocks, 1), dim3(256), 0, stream,
                       ws + WS_X2, iW0, ib0, iW1, ib1, iW2, ib2, iW3, ib3, ws,
                       out + n, out + n, 2, n);
}

// Round 6
// 622.526 us; speedup vs baseline: 2.3432x; 2.3432x over previous
//
#include <hip/hip_runtime.h>
#include <hip/hip_bf16.h>
#include <math.h>

typedef short bf16x8 __attribute__((ext_vector_type(8)));
typedef float f32x16 __attribute__((ext_vector_type(16)));

#define DH 100      // hidden dim
#define SPB 20      // samples per block -> 2020 rows, padded to 2048
#define NCH 16      // chunks of 128 rows
#define WSTR 136    // LDS row stride in bf16 elems (272 B => near-conflict-free b128)

// ws float offsets
#define WS_CCW   0
#define WS_XSC   128
#define WS_OH0   256
#define WS_EOH1  260
#define WS_X2    272

__device__ __forceinline__ unsigned short f2bf(float f) {
    unsigned int u = __float_as_uint(f);
    unsigned int r = (u + 0x7FFFu + ((u >> 16) & 1u)) >> 16;  // RNE
    return (unsigned short)r;
}
__device__ __forceinline__ unsigned int pk2(float a, float b) {
    // packed f32->bf16 (v_cvt_pk_bf16_f32); low u16 = a
    __hip_bfloat162 h = __float22bfloat162_rn(make_float2(a, b));
    union { __hip_bfloat162 h; unsigned int u; } c; c.h = h; return c.u;
}

__global__ void setup_kernel(const float* __restrict__ logits,
                             const float* __restrict__ hb0,
                             const float* __restrict__ hW1,
                             const float* __restrict__ hb1,
                             const float* __restrict__ hW2,
                             const float* __restrict__ hb2,
                             const float* __restrict__ hW3,
                             const float* __restrict__ hb3,
                             float* __restrict__ ws,
                             float* __restrict__ out2, int n)
{
    int t = threadIdx.x;
    for (int i = blockIdx.x * blockDim.x + t; i < n; i += gridDim.x * blockDim.x)
        out2[i] = logits[i];
    if (blockIdx.x != 0) return;

    if (t < 128) {
        double ccw = 0.0, xs = 0.0;
        if (t <= 100) {
            double s = (double)t;
            for (int j = 0; j <= 100; j += 2) {
                double wj = (j == 0) ? 1.0 : 2.0 / (1.0 - (double)j * (double)j);
                double lam;
                if (t == 0) lam = 0.5;
                else {
                    lam = cos((double)j * s * M_PI / 100.0);
                    if (t == 100) lam *= 0.5;
                }
                ccw += lam * 0.02 * wj;
            }
            xs = (cos(s * M_PI / 100.0) + 1.0) * 0.5;
        }
        ws[WS_CCW + t] = (float)ccw;
        ws[WS_XSC + t] = (float)xs;
    }
    __syncthreads();

    __shared__ float bufA[DH], bufB[DH];
    for (int k = 0; k < 3; ++k) {
        if (t < DH) bufA[t] = fmaxf(hb0[k * DH + t], 0.f);
        __syncthreads();
        if (t < DH) {
            float acc = hb1[k * DH + t];
            const float* w = hW1 + (size_t)(k * DH + t) * DH;
            for (int i = 0; i < DH; ++i) acc = fmaf(w[i], bufA[i], acc);
            bufB[t] = fmaxf(acc, 0.f);
        }
        __syncthreads();
        if (t < DH) {
            float acc = hb2[k * DH + t];
            const float* w = hW2 + (size_t)(k * DH + t) * DH;
            for (int i = 0; i < DH; ++i) acc = fmaf(w[i], bufB[i], acc);
            bufA[t] = fmaxf(acc, 0.f);
        }
        __syncthreads();
        if (t < 2) {
            float acc = hb3[k * 2 + t];
            const float* w = hW3 + (size_t)(k * 2 + t) * DH;
            for (int i = 0; i < DH; ++i) acc = fmaf(w[i], bufA[i], acc);
            if (t == 0) ws[WS_OH0 + k] = acc;
            else        ws[WS_EOH1 + k] = expf(acc);
        }
        __syncthreads();
    }
}

// Transposed dataflow (verified R3-R5): C1 = W1·A1^T, C2 = W2·A2^T; inter-layer
// C->B-operand transform via lane^32 shuffle exchange. All weight/const LDS
// reads inside the chunk loop are laundered through an opaque zero offset
// (asm "+v") so LICM cannot hoist them into a >256-reg register cache (the
// R4/R5 spill cause). Weights stay LDS-resident; live regs ~140.
__global__ __launch_bounds__(256)
void mono_mfma(const float* __restrict__ xsrc,
               const float* __restrict__ iW0, const float* __restrict__ ib0,
               const float* __restrict__ iW1, const float* __restrict__ ib1,
               const float* __restrict__ iW2, const float* __restrict__ ib2,
               const float* __restrict__ iW3, const float* __restrict__ ib3,
               const float* __restrict__ ws,
               float* __restrict__ dst0, float* __restrict__ dst1,
               int kbase, int nTot)
{
    __shared__ __align__(16) unsigned short W1s[DH * WSTR];  // row n1<100, col kin; col 100 = b1
    __shared__ __align__(16) unsigned short W2s[DH * WSTR];  // row n2<100, col n1;  col 100 = b2
    __shared__ unsigned int wb_s[128];    // packed (bf16(b0)<<16)|bf16(w0); slot 100 = (1.0, 0)
    __shared__ unsigned int w3p_s[64];    // packed bf16 w3 pairs, [hf][nt2][q][pr]; 0 for n2>=100
    __shared__ float xsc_s[128], ccw_s[128];
    __shared__ float xs_s[32], zs[32];

    const int tid = threadIdx.x;
    const int lane = tid & 63;
    const int wv = tid >> 6;
    const int hf = lane >> 5;
    const bool hfb = (hf != 0);
    const int l31 = lane & 31;
    const int k = kbase + blockIdx.y;
    float* __restrict__ dst = (blockIdx.y == 0) ? dst0 : dst1;

    const float* W1g = iW1 + (size_t)k * DH * DH;
    const float* W2g = iW2 + (size_t)k * DH * DH;

    if (tid < 128) {
        xsc_s[tid] = ws[WS_XSC + tid];
        ccw_s[tid] = ws[WS_CCW + tid];
        float w0 = (tid < DH) ? iW0[(k * DH + tid) * 3] : 0.f;   // h==0: feature 0 only
        float b0 = (tid < DH) ? ib0[k * DH + tid] : ((tid == DH) ? 1.f : 0.f);
        wb_s[tid] = ((unsigned int)f2bf(b0) << 16) | (unsigned int)f2bf(w0);
    }
    if (tid < 64) {
        int hf_i = tid >> 5, rem = tid & 31;
        int nt2 = rem >> 3, qq = (rem >> 1) & 3, pr = rem & 1;
        int n2e = 32 * nt2 + 8 * qq + 2 * pr + 4 * hf_i;
        float we = (n2e < DH) ? iW3[k * DH + n2e] : 0.f;
        float wo = (n2e + 1 < DH) ? iW3[k * DH + n2e + 1] : 0.f;
        w3p_s[tid] = ((unsigned int)f2bf(wo) << 16) | (unsigned int)f2bf(we);
    }
    if (tid < 32) {
        int n = blockIdx.x * SPB + tid;
        xs_s[tid] = (tid < SPB && n < nTot) ? xsrc[n] : 0.f;
        zs[tid] = 0.f;
    }
    // stage W1/W2 (100 rows x 128 cols; col 100 = bias, 101..127 = 0)
    for (int i = tid; i < DH * 128; i += 256) {
        int r = i >> 7, c = i & 127;
        float v1, v2;
        if (c < DH)       { v1 = W1g[r * DH + c]; v2 = W2g[r * DH + c]; }
        else if (c == DH) { v1 = ib1[k * DH + r]; v2 = ib2[k * DH + r]; }
        else              { v1 = 0.f; v2 = 0.f; }
        W1s[r * WSTR + c] = f2bf(v1);
        W2s[r * WSTR + c] = f2bf(v2);
    }
    __syncthreads();

    const float b3 = ib3[k];
    const float e1 = ws[WS_EOH1 + k];
    const float o0 = ws[WS_OH0 + k];

    // per-lane weight-fragment LDS base offsets (row clamped to 99)
    int wrow[4];
    #pragma unroll
    for (int nt = 0; nt < 4; ++nt) {
        int r = nt * 32 + l31;
        wrow[nt] = ((r > DH - 1) ? (DH - 1) : r) * WSTR + hf * 8;
    }

    union FR { bf16x8 v; unsigned int u32[4]; };

    #pragma unroll 1
    for (int ch = 0; ch < NCH; ++ch) {
        // Opaque zero: every LDS read below depends on it -> LICM blocked.
        unsigned int zoff = 0;
        asm volatile("" : "+v"(zoff));

        const int mrow = ch * 128 + wv * 32 + l31;
        const int nloc = (mrow * 649) >> 16;   // mrow / 101
        const int p = mrow - nloc * 101;
        const float u = xs_s[nloc] * xsc_s[p];

        // ---- layer 1: build all 8 B-frags (rank-1 in u; bias in slot 100) ----
        FR a1[8];
        #pragma unroll
        for (int ks = 0; ks < 8; ++ks) {
            const unsigned int* wb = &wb_s[ks * 16 + hf * 8 + zoff];
            uint4 qa = *(const uint4*)wb;
            uint4 qb = *(const uint4*)(wb + 4);
            unsigned int q[8] = {qa.x, qa.y, qa.z, qa.w, qb.x, qb.y, qb.z, qb.w};
            float v[8];
            #pragma unroll
            for (int j = 0; j < 8; ++j) {
                float w0 = __uint_as_float(q[j] << 16);
                float b0 = __uint_as_float(q[j] & 0xFFFF0000u);
                v[j] = fmaxf(fmaf(u, w0, b0), 0.f);
            }
            a1[ks].u32[0] = pk2(v[0], v[1]);
            a1[ks].u32[1] = pk2(v[2], v[3]);
            a1[ks].u32[2] = pk2(v[4], v[5]);
            a1[ks].u32[3] = pk2(v[6], v[7]);
        }

        // ---- layer 2: nt-outer, one 16-reg accumulator; pack+exchange -> f3 ----
        FR f3[8];
        #pragma unroll
        for (int nt = 0; nt < 4; ++nt) {
            f32x16 acc;
            #pragma unroll
            for (int r = 0; r < 16; ++r) acc[r] = 0.f;
            #pragma unroll
            for (int ks = 0; ks < 8; ++ks) {
                bf16x8 wA = *(const bf16x8*)&W1s[wrow[nt] + ks * 16 + zoff];
                acc = __builtin_amdgcn_mfma_f32_32x32x16_bf16(wA, a1[ks].v, acc, 0, 0, 0);
            }
            unsigned int pk[4][2];
            #pragma unroll
            for (int qi = 0; qi < 4; ++qi) {
                float a0 = fmaxf(acc[4 * qi + 0], 0.f);
                float a1v = fmaxf(acc[4 * qi + 1], 0.f);
                float a2 = fmaxf(acc[4 * qi + 2], 0.f);
                float a3 = fmaxf(acc[4 * qi + 3], 0.f);
                pk[qi][0] = pk2(a0, a1v);
                pk[qi][1] = pk2(a2, a3);
            }
            #pragma unroll
            for (int kk = 0; kk < 2; ++kk) {
                unsigned int X0 = hfb ? pk[2 * kk][0] : pk[2 * kk + 1][0];
                unsigned int X1 = hfb ? pk[2 * kk][1] : pk[2 * kk + 1][1];
                unsigned int O0 = hfb ? pk[2 * kk + 1][0] : pk[2 * kk][0];
                unsigned int O1 = hfb ? pk[2 * kk + 1][1] : pk[2 * kk][1];
                unsigned int Y0 = (unsigned int)__shfl_xor((int)X0, 32, 64);
                unsigned int Y1 = (unsigned int)__shfl_xor((int)X1, 32, 64);
                f3[nt * 2 + kk].u32[0] = hfb ? Y0 : O0;
                f3[nt * 2 + kk].u32[1] = hfb ? Y1 : O1;
                f3[nt * 2 + kk].u32[2] = hfb ? O0 : Y0;
                f3[nt * 2 + kk].u32[3] = hfb ? O1 : Y1;
            }
        }
        // bias slot n1=100 := 1.0 exactly (hf=0 low half of f3[6].u32[2]);
        // n1=101..127 garbage is killed by zero W2 columns.
        f3[6].u32[2] = hfb ? f3[6].u32[2]
                           : ((f3[6].u32[2] & 0xFFFF0000u) | 0x00003F80u);

        // ---- layer 3: nt2-outer, one accumulator; fold w3 (from LDS) ----
        float oacc = 0.f;
        #pragma unroll
        for (int nt2 = 0; nt2 < 4; ++nt2) {
            f32x16 acc2;
            #pragma unroll
            for (int r = 0; r < 16; ++r) acc2[r] = 0.f;
            #pragma unroll
            for (int ks = 0; ks < 8; ++ks) {
                bf16x8 wA = *(const bf16x8*)&W2s[wrow[nt2] + ks * 16 + zoff];
                acc2 = __builtin_amdgcn_mfma_f32_32x32x16_bf16(wA, f3[ks].v, acc2, 0, 0, 0);
            }
            uint4 wa = *(const uint4*)&w3p_s[hf * 32 + nt2 * 8 + zoff];
            uint4 wb2 = *(const uint4*)&w3p_s[hf * 32 + nt2 * 8 + 4 + zoff];
            unsigned int w8[8] = {wa.x, wa.y, wa.z, wa.w, wb2.x, wb2.y, wb2.z, wb2.w};
            #pragma unroll
            for (int r = 0; r < 16; ++r) {
                int qi = r >> 2, s = r & 3;
                unsigned int wu = w8[qi * 2 + (s >> 1)];
                float w3v = __uint_as_float((s & 1) ? (wu & 0xFFFF0000u) : (wu << 16));
                oacc = fmaf(fmaxf(acc2[r], 0.f), w3v, oacc);
            }
        }

        float o = oacc + __shfl_xor(oacc, 32, 64) + b3;
        float dz = (o > 0.f) ? (o + 1.f) : expf(o);   // elu(o) + 1
        float val = dz * ccw_s[p];
        int nA = __shfl(nloc, 0, 32);
        int nB = __shfl(nloc, 31, 32);
        float vA = (nloc == nA) ? val : 0.f;
        vA += __shfl_xor(vA, 16, 32);
        vA += __shfl_xor(vA, 8, 32);
        vA += __shfl_xor(vA, 4, 32);
        vA += __shfl_xor(vA, 2, 32);
        vA += __shfl_xor(vA, 1, 32);
        if (lane == 0) atomicAdd(&zs[nA], vA);
        if (nB != nA) {
            float vB = (nloc == nB) ? val : 0.f;
            vB += __shfl_xor(vB, 16, 32);
            vB += __shfl_xor(vB, 8, 32);
            vB += __shfl_xor(vB, 4, 32);
            vB += __shfl_xor(vB, 2, 32);
            vB += __shfl_xor(vB, 1, 32);
            if (lane == 1) atomicAdd(&zs[nB], vB);
        }
    }

    __syncthreads();
    if (tid < SPB) {
        int n = blockIdx.x * SPB + tid;
        if (n < nTot) dst[n] = fmaf(e1, 0.5f * xs_s[tid] * zs[tid], o0);
    }
}

extern "C" void kernel_launch(void* const* d_in, const int* in_sizes, int n_in,
                              void* d_out, int out_size, void* d_ws, size_t ws_size,
                              hipStream_t stream)
{
    const float* logits = (const float*)d_in[0];
    const float* iW0 = (const float*)d_in[2];
    const float* ib0 = (const float*)d_in[3];
    const float* iW1 = (const float*)d_in[4];
    const float* ib1 = (const float*)d_in[5];
    const float* iW2 = (const float*)d_in[6];
    const float* ib2 = (const float*)d_in[7];
    const float* iW3 = (const float*)d_in[8];
    const float* ib3 = (const float*)d_in[9];
    const float* hb0 = (const float*)d_in[11];
    const float* hW1 = (const float*)d_in[12];
    const float* hb1 = (const float*)d_in[13];
    const float* hW2 = (const float*)d_in[14];
    const float* hb2 = (const float*)d_in[15];
    const float* hW3 = (const float*)d_in[16];
    const float* hb3 = (const float*)d_in[17];
    float* out = (float*)d_out;
    float* ws = (float*)d_ws;
    int n = in_sizes[0];
    int nblocks = (n + SPB - 1) / SPB;

    hipLaunchKernelGGL(setup_kernel, dim3(64), dim3(256), 0, stream,
                       logits, hb0, hW1, hb1, hW2, hb2, hW3, hb3, ws, out + 2 * n, n);
    // phase A: k=0 -> x2 (workspace), k=1 -> y1
    hipLaunchKernelGGL(mono_mfma, dim3(nblocks, 2), dim3(256), 0, stream,
                       logits, iW0, ib0, iW1, ib1, iW2, ib2, iW3, ib3, ws,
                       ws + WS_X2, out, 0, n);
    // phase B: k=2 on x2 -> y2
    hipLaunchKernelGGL(mono_mfma, dim3(nblocks, 1), dim3(256), 0, stream,
                       ws + WS_X2, iW0, ib0, iW1, ib1, iW2, ib2, iW3, ib3, ws,
                       out + n, out + n, 2, n);
}

// Round 7
// 549.207 us; speedup vs baseline: 2.6560x; 1.1335x over previous
//
#include <hip/hip_runtime.h>
#include <hip/hip_bf16.h>
#include <math.h>

typedef short bf16x8 __attribute__((ext_vector_type(8)));
typedef float f32x16 __attribute__((ext_vector_type(16)));

#define DH 100      // hidden dim
#define SPB 20      // samples per block -> 2020 rows, padded to 2048
#define NCH 16      // chunks of 128 rows
#define WSTR 120    // LDS row stride in bf16 elems (240 B, 16B-aligned; cols 0..119)

// ws float offsets
#define WS_CCW   0
#define WS_XSC   128
#define WS_OH0   256
#define WS_EOH1  260
#define WS_X2    272

__device__ __forceinline__ unsigned short f2bf(float f) {
    unsigned int u = __float_as_uint(f);
    unsigned int r = (u + 0x7FFFu + ((u >> 16) & 1u)) >> 16;  // RNE
    return (unsigned short)r;
}
__device__ __forceinline__ unsigned int pk2(float a, float b) {
    // packed f32->bf16 (v_cvt_pk_bf16_f32); low u16 = a
    __hip_bfloat162 h = __float22bfloat162_rn(make_float2(a, b));
    union { __hip_bfloat162 h; unsigned int u; } c; c.h = h; return c.u;
}

__global__ void setup_kernel(const float* __restrict__ logits,
                             const float* __restrict__ hb0,
                             const float* __restrict__ hW1,
                             const float* __restrict__ hb1,
                             const float* __restrict__ hW2,
                             const float* __restrict__ hb2,
                             const float* __restrict__ hW3,
                             const float* __restrict__ hb3,
                             float* __restrict__ ws,
                             float* __restrict__ out2, int n)
{
    int t = threadIdx.x;
    for (int i = blockIdx.x * blockDim.x + t; i < n; i += gridDim.x * blockDim.x)
        out2[i] = logits[i];
    if (blockIdx.x != 0) return;

    if (t < 128) {
        double ccw = 0.0, xs = 0.0;
        if (t <= 100) {
            double s = (double)t;
            for (int j = 0; j <= 100; j += 2) {
                double wj = (j == 0) ? 1.0 : 2.0 / (1.0 - (double)j * (double)j);
                double lam;
                if (t == 0) lam = 0.5;
                else {
                    lam = cos((double)j * s * M_PI / 100.0);
                    if (t == 100) lam *= 0.5;
                }
                ccw += lam * 0.02 * wj;
            }
            xs = (cos(s * M_PI / 100.0) + 1.0) * 0.5;
        }
        ws[WS_CCW + t] = (float)ccw;
        ws[WS_XSC + t] = (float)xs;
    }
    __syncthreads();

    __shared__ float bufA[DH], bufB[DH];
    for (int k = 0; k < 3; ++k) {
        if (t < DH) bufA[t] = fmaxf(hb0[k * DH + t], 0.f);
        __syncthreads();
        if (t < DH) {
            float acc = hb1[k * DH + t];
            const float* w = hW1 + (size_t)(k * DH + t) * DH;
            for (int i = 0; i < DH; ++i) acc = fmaf(w[i], bufA[i], acc);
            bufB[t] = fmaxf(acc, 0.f);
        }
        __syncthreads();
        if (t < DH) {
            float acc = hb2[k * DH + t];
            const float* w = hW2 + (size_t)(k * DH + t) * DH;
            for (int i = 0; i < DH; ++i) acc = fmaf(w[i], bufB[i], acc);
            bufA[t] = fmaxf(acc, 0.f);
        }
        __syncthreads();
        if (t < 2) {
            float acc = hb3[k * 2 + t];
            const float* w = hW3 + (size_t)(k * 2 + t) * DH;
            for (int i = 0; i < DH; ++i) acc = fmaf(w[i], bufA[i], acc);
            if (t == 0) ws[WS_OH0 + k] = acc;
            else        ws[WS_EOH1 + k] = expf(acc);
        }
        __syncthreads();
    }
}

// Transposed dataflow (verified R3-R6): C1 = W1·A1^T, C2 = W2·A2^T; inter-layer
// C->B-operand transform via lane^32 shuffle exchange. LDS reads in the chunk
// loop are laundered through an opaque zero offset so LICM can't build a
// >256-reg weight cache (R4/R5 spill cause). New in R7: k-slots 101..127 are
// structurally zero -> ks=7 skipped in both layers (56 MFMAs not 64), W-stride
// 120 (LDS ~50 KB -> 3 blocks/CU), w3 held as fp32 registers (not laundered).
__global__ __launch_bounds__(256)
void mono_mfma(const float* __restrict__ xsrc,
               const float* __restrict__ iW0, const float* __restrict__ ib0,
               const float* __restrict__ iW1, const float* __restrict__ ib1,
               const float* __restrict__ iW2, const float* __restrict__ ib2,
               const float* __restrict__ iW3, const float* __restrict__ ib3,
               const float* __restrict__ ws,
               float* __restrict__ dst0, float* __restrict__ dst1,
               int kbase, int nTot)
{
    __shared__ __align__(16) unsigned short W1s[DH * WSTR];  // row n1<100, col kin<120; col 100 = b1
    __shared__ __align__(16) unsigned short W2s[DH * WSTR];  // row n2<100, col n1<120;  col 100 = b2
    __shared__ unsigned int wb_s[128];    // packed (bf16(b0)<<16)|bf16(w0); slot 100 = (1.0, 0); 101..127 = 0
    __shared__ unsigned int w3p_s[64];    // packed bf16 w3 pairs, [hf][nt2][q][pr]; 0 for n2>=100
    __shared__ float xsc_s[128], ccw_s[128];
    __shared__ float xs_s[32], zs[32];

    const int tid = threadIdx.x;
    const int lane = tid & 63;
    const int wv = tid >> 6;
    const int hf = lane >> 5;
    const bool hfb = (hf != 0);
    const int l31 = lane & 31;
    const int k = kbase + blockIdx.y;
    float* __restrict__ dst = (blockIdx.y == 0) ? dst0 : dst1;

    const float* W1g = iW1 + (size_t)k * DH * DH;
    const float* W2g = iW2 + (size_t)k * DH * DH;

    if (tid < 128) {
        xsc_s[tid] = ws[WS_XSC + tid];
        ccw_s[tid] = ws[WS_CCW + tid];
        float w0 = (tid < DH) ? iW0[(k * DH + tid) * 3] : 0.f;   // h==0: feature 0 only
        float b0 = (tid < DH) ? ib0[k * DH + tid] : ((tid == DH) ? 1.f : 0.f);
        wb_s[tid] = ((unsigned int)f2bf(b0) << 16) | (unsigned int)f2bf(w0);
    }
    if (tid < 64) {
        int hf_i = tid >> 5, rem = tid & 31;
        int nt2 = rem >> 3, qq = (rem >> 1) & 3, pr = rem & 1;
        int n2e = 32 * nt2 + 8 * qq + 2 * pr + 4 * hf_i;
        float we = (n2e < DH) ? iW3[k * DH + n2e] : 0.f;
        float wo = (n2e + 1 < DH) ? iW3[k * DH + n2e + 1] : 0.f;
        w3p_s[tid] = ((unsigned int)f2bf(wo) << 16) | (unsigned int)f2bf(we);
    }
    if (tid < 32) {
        int n = blockIdx.x * SPB + tid;
        xs_s[tid] = (tid < SPB && n < nTot) ? xsrc[n] : 0.f;
        zs[tid] = 0.f;
    }
    // stage W1/W2 (100 rows x 120 cols; col 100 = bias, 101..119 = 0)
    for (int i = tid; i < DH * WSTR; i += 256) {
        int r = i / WSTR, c = i - r * WSTR;
        float v1, v2;
        if (c < DH)       { v1 = W1g[r * DH + c]; v2 = W2g[r * DH + c]; }
        else if (c == DH) { v1 = ib1[k * DH + r]; v2 = ib2[k * DH + r]; }
        else              { v1 = 0.f; v2 = 0.f; }
        W1s[r * WSTR + c] = f2bf(v1);
        W2s[r * WSTR + c] = f2bf(v2);
    }
    __syncthreads();

    const float b3 = ib3[k];
    const float e1 = ws[WS_EOH1 + k];
    const float o0 = ws[WS_OH0 + k];

    // w3 as fp32 in registers (NOT laundered -- we want these hoisted).
    float w3f[64];
    #pragma unroll
    for (int j = 0; j < 32; ++j) {
        unsigned int wu = w3p_s[hf * 32 + j];
        w3f[2 * j]     = __uint_as_float(wu << 16);
        w3f[2 * j + 1] = __uint_as_float(wu & 0xFFFF0000u);
    }

    // per-lane weight-fragment LDS base offsets (row clamped to 99)
    int wrow[4];
    #pragma unroll
    for (int nt = 0; nt < 4; ++nt) {
        int r = nt * 32 + l31;
        wrow[nt] = ((r > DH - 1) ? (DH - 1) : r) * WSTR + hf * 8;
    }

    union FR { bf16x8 v; unsigned int u32[4]; };

    #pragma unroll 1
    for (int ch = 0; ch < NCH; ++ch) {
        // Opaque zero: every LDS read below depends on it -> LICM blocked.
        unsigned int zoff = 0;
        asm volatile("" : "+v"(zoff));

        const int mrow = ch * 128 + wv * 32 + l31;
        const int nloc = (mrow * 649) >> 16;   // mrow / 101
        const int p = mrow - nloc * 101;
        const float u = xs_s[nloc] * xsc_s[p];

        // ---- layer 1: build B-frags ks=0..6 (rank-1 in u; bias in slot 100) ----
        FR a1[7];
        #pragma unroll
        for (int ks = 0; ks < 7; ++ks) {
            const unsigned int* wb = &wb_s[ks * 16 + hf * 8 + zoff];
            uint4 qa = *(const uint4*)wb;
            uint4 qb = *(const uint4*)(wb + 4);
            unsigned int q[8] = {qa.x, qa.y, qa.z, qa.w, qb.x, qb.y, qb.z, qb.w};
            float v[8];
            #pragma unroll
            for (int j = 0; j < 8; ++j) {
                float w0 = __uint_as_float(q[j] << 16);
                float b0 = __uint_as_float(q[j] & 0xFFFF0000u);
                v[j] = fmaxf(fmaf(u, w0, b0), 0.f);
            }
            a1[ks].u32[0] = pk2(v[0], v[1]);
            a1[ks].u32[1] = pk2(v[2], v[3]);
            a1[ks].u32[2] = pk2(v[4], v[5]);
            a1[ks].u32[3] = pk2(v[6], v[7]);
        }

        // ---- layer 2: nt-outer, one 16-reg accumulator; pack+exchange -> f3 ----
        FR f3[7];
        #pragma unroll
        for (int nt = 0; nt < 4; ++nt) {
            f32x16 acc;
            #pragma unroll
            for (int r = 0; r < 16; ++r) acc[r] = 0.f;
            #pragma unroll
            for (int ks = 0; ks < 7; ++ks) {
                bf16x8 wA = *(const bf16x8*)&W1s[wrow[nt] + ks * 16 + zoff];
                acc = __builtin_amdgcn_mfma_f32_32x32x16_bf16(wA, a1[ks].v, acc, 0, 0, 0);
            }
            if (nt < 3) {
                unsigned int pk[4][2];
                #pragma unroll
                for (int qi = 0; qi < 4; ++qi) {
                    float a0 = fmaxf(acc[4 * qi + 0], 0.f);
                    float a1v = fmaxf(acc[4 * qi + 1], 0.f);
                    float a2 = fmaxf(acc[4 * qi + 2], 0.f);
                    float a3 = fmaxf(acc[4 * qi + 3], 0.f);
                    pk[qi][0] = pk2(a0, a1v);
                    pk[qi][1] = pk2(a2, a3);
                }
                #pragma unroll
                for (int kk = 0; kk < 2; ++kk) {
                    unsigned int X0 = hfb ? pk[2 * kk][0] : pk[2 * kk + 1][0];
                    unsigned int X1 = hfb ? pk[2 * kk][1] : pk[2 * kk + 1][1];
                    unsigned int O0 = hfb ? pk[2 * kk + 1][0] : pk[2 * kk][0];
                    unsigned int O1 = hfb ? pk[2 * kk + 1][1] : pk[2 * kk][1];
                    unsigned int Y0 = (unsigned int)__shfl_xor((int)X0, 32, 64);
                    unsigned int Y1 = (unsigned int)__shfl_xor((int)X1, 32, 64);
                    f3[nt * 2 + kk].u32[0] = hfb ? Y0 : O0;
                    f3[nt * 2 + kk].u32[1] = hfb ? Y1 : O1;
                    f3[nt * 2 + kk].u32[2] = hfb ? O0 : Y0;
                    f3[nt * 2 + kk].u32[3] = hfb ? O1 : Y1;
                }
            } else {
                // nt=3 tile: only rows 96..99 are real, and only hf0 readers
                // (k=96..103) consume them. No exchange needed:
                //   hf0: u32[0..1] = rows 96..99 (own qi=0), u32[2] = bias 1.0
                //        at k=100 (high half k=101 -> 0), u32[3] = 0 (k=102,103)
                //   hf1: k=104..111 all structurally zero.
                float a0 = fmaxf(acc[0], 0.f);
                float a1v = fmaxf(acc[1], 0.f);
                float a2 = fmaxf(acc[2], 0.f);
                float a3 = fmaxf(acc[3], 0.f);
                unsigned int p0 = pk2(a0, a1v);
                unsigned int p1 = pk2(a2, a3);
                f3[6].u32[0] = hfb ? 0u : p0;
                f3[6].u32[1] = hfb ? 0u : p1;
                f3[6].u32[2] = hfb ? 0u : 0x00003F80u;
                f3[6].u32[3] = 0u;
            }
        }

        // ---- layer 3: nt2-outer, one accumulator; fold w3 (fp32 regs) ----
        float oacc = 0.f;
        #pragma unroll
        for (int nt2 = 0; nt2 < 4; ++nt2) {
            f32x16 acc2;
            #pragma unroll
            for (int r = 0; r < 16; ++r) acc2[r] = 0.f;
            #pragma unroll
            for (int ks = 0; ks < 7; ++ks) {
                bf16x8 wA = *(const bf16x8*)&W2s[wrow[nt2] + ks * 16 + zoff];
                acc2 = __builtin_amdgcn_mfma_f32_32x32x16_bf16(wA, f3[ks].v, acc2, 0, 0, 0);
            }
            #pragma unroll
            for (int r = 0; r < 16; ++r) {
                int qi = r >> 2, s = r & 3;
                float w3v = w3f[2 * (nt2 * 8 + qi * 2 + (s >> 1)) + (s & 1)];
                oacc = fmaf(fmaxf(acc2[r], 0.f), w3v, oacc);
            }
        }

        float o = oacc + __shfl_xor(oacc, 32, 64) + b3;
        float dz = (o > 0.f) ? (o + 1.f) : expf(o);   // elu(o) + 1
        float val = dz * ccw_s[p];
        int nA = __shfl(nloc, 0, 32);
        int nB = __shfl(nloc, 31, 32);
        float vA = (nloc == nA) ? val : 0.f;
        vA += __shfl_xor(vA, 16, 32);
        vA += __shfl_xor(vA, 8, 32);
        vA += __shfl_xor(vA, 4, 32);
        vA += __shfl_xor(vA, 2, 32);
        vA += __shfl_xor(vA, 1, 32);
        if (lane == 0) atomicAdd(&zs[nA], vA);
        if (nB != nA) {
            float vB = (nloc == nB) ? val : 0.f;
            vB += __shfl_xor(vB, 16, 32);
            vB += __shfl_xor(vB, 8, 32);
            vB += __shfl_xor(vB, 4, 32);
            vB += __shfl_xor(vB, 2, 32);
            vB += __shfl_xor(vB, 1, 32);
            if (lane == 1) atomicAdd(&zs[nB], vB);
        }
    }

    __syncthreads();
    if (tid < SPB) {
        int n = blockIdx.x * SPB + tid;
        if (n < nTot) dst[n] = fmaf(e1, 0.5f * xs_s[tid] * zs[tid], o0);
    }
}

extern "C" void kernel_launch(void* const* d_in, const int* in_sizes, int n_in,
                              void* d_out, int out_size, void* d_ws, size_t ws_size,
                              hipStream_t stream)
{
    const float* logits = (const float*)d_in[0];
    const float* iW0 = (const float*)d_in[2];
    const float* ib0 = (const float*)d_in[3];
    const float* iW1 = (const float*)d_in[4];
    const float* ib1 = (const float*)d_in[5];
    const float* iW2 = (const float*)d_in[6];
    const float* ib2 = (const float*)d_in[7];
    const float* iW3 = (const float*)d_in[8];
    const float* ib3 = (const float*)d_in[9];
    const float* hb0 = (const float*)d_in[11];
    const float* hW1 = (const float*)d_in[12];
    const float* hb1 = (const float*)d_in[13];
    const float* hW2 = (const float*)d_in[14];
    const float* hb2 = (const float*)d_in[15];
    const float* hW3 = (const float*)d_in[16];
    const float* hb3 = (const float*)d_in[17];
    float* out = (float*)d_out;
    float* ws = (float*)d_ws;
    int n = in_sizes[0];
    int nblocks = (n + SPB - 1) / SPB;

    hipLaunchKernelGGL(setup_kernel, dim3(64), dim3(256), 0, stream,
                       logits, hb0, hW1, hb1, hW2, hb2, hW3, hb3, ws, out + 2 * n, n);
    // phase A: k=0 -> x2 (workspace), k=1 -> y1
    hipLaunchKernelGGL(mono_mfma, dim3(nblocks, 2), dim3(256), 0, stream,
                       logits, iW0, ib0, iW1, ib1, iW2, ib2, iW3, ib3, ws,
                       ws + WS_X2, out, 0, n);
    // phase B: k=2 on x2 -> y2
    hipLaunchKernelGGL(mono_mfma, dim3(nblocks, 1), dim3(256), 0, stream,
                       ws + WS_X2, iW0, ib0, iW1, ib1, iW2, ib2, iW3, ib3, ws,
                       out + n, out + n, 2, n);
}

// Round 9
// 530.829 us; speedup vs baseline: 2.7480x; 1.0346x over previous
//
#include <hip/hip_runtime.h>
#include <hip/hip_bf16.h>
#include <hip/hip_fp16.h>
#include <math.h>

typedef _Float16 f16x8 __attribute__((ext_vector_type(8)));
typedef _Float16 h2 __attribute__((ext_vector_type(2)));
typedef __fp16 h2amd __attribute__((ext_vector_type(2)));   // builtin return type
typedef float f32x16 __attribute__((ext_vector_type(16)));

#define DH 100      // hidden dim
#define SPB 20      // samples per block -> 2020 rows, padded to 2048
#define NCH 16      // chunks of 128 rows
#define WSTR 120    // LDS row stride in f16 elems (240 B, 16B-aligned; cols 0..119)

// ws float offsets
#define WS_CCW   0
#define WS_XSC   128
#define WS_OH0   256
#define WS_EOH1  260
#define WS_X2    272

__device__ __forceinline__ unsigned short f2bf(float f) {
    unsigned int u = __float_as_uint(f);
    unsigned int r = (u + 0x7FFFu + ((u >> 16) & 1u)) >> 16;  // RNE
    return (unsigned short)r;
}
__device__ __forceinline__ unsigned int hpk(float a, float b) {
    // v_cvt_pkrtz_f16_f32: low u16 = f16(a), high = f16(b)
    union { h2amd h; unsigned int u; } c;
    c.h = __builtin_amdgcn_cvt_pkrtz(a, b);
    return c.u;
}
__device__ __forceinline__ h2 hpk2(float a, float b) {
    union { h2amd ha; h2 h; } c;
    c.ha = __builtin_amdgcn_cvt_pkrtz(a, b);
    return c.h;
}

__global__ void setup_kernel(const float* __restrict__ logits,
                             const float* __restrict__ hb0,
                             const float* __restrict__ hW1,
                             const float* __restrict__ hb1,
                             const float* __restrict__ hW2,
                             const float* __restrict__ hb2,
                             const float* __restrict__ hW3,
                             const float* __restrict__ hb3,
                             float* __restrict__ ws,
                             float* __restrict__ out2, int n)
{
    int t = threadIdx.x;
    for (int i = blockIdx.x * blockDim.x + t; i < n; i += gridDim.x * blockDim.x)
        out2[i] = logits[i];
    if (blockIdx.x != 0) return;

    if (t < 128) {
        double ccw = 0.0, xs = 0.0;
        if (t <= 100) {
            double s = (double)t;
            for (int j = 0; j <= 100; j += 2) {
                double wj = (j == 0) ? 1.0 : 2.0 / (1.0 - (double)j * (double)j);
                double lam;
                if (t == 0) lam = 0.5;
                else {
                    lam = cos((double)j * s * M_PI / 100.0);
                    if (t == 100) lam *= 0.5;
                }
                ccw += lam * 0.02 * wj;
            }
            xs = (cos(s * M_PI / 100.0) + 1.0) * 0.5;
        }
        ws[WS_CCW + t] = (float)ccw;
        ws[WS_XSC + t] = (float)xs;
    }
    __syncthreads();

    __shared__ float bufA[DH], bufB[DH];
    for (int k = 0; k < 3; ++k) {
        if (t < DH) bufA[t] = fmaxf(hb0[k * DH + t], 0.f);
        __syncthreads();
        if (t < DH) {
            float acc = hb1[k * DH + t];
            const float* w = hW1 + (size_t)(k * DH + t) * DH;
            for (int i = 0; i < DH; ++i) acc = fmaf(w[i], bufA[i], acc);
            bufB[t] = fmaxf(acc, 0.f);
        }
        __syncthreads();
        if (t < DH) {
            float acc = hb2[k * DH + t];
            const float* w = hW2 + (size_t)(k * DH + t) * DH;
            for (int i = 0; i < DH; ++i) acc = fmaf(w[i], bufB[i], acc);
            bufA[t] = fmaxf(acc, 0.f);
        }
        __syncthreads();
        if (t < 2) {
            float acc = hb3[k * 2 + t];
            const float* w = hW3 + (size_t)(k * 2 + t) * DH;
            for (int i = 0; i < DH; ++i) acc = fmaf(w[i], bufA[i], acc);
            if (t == 0) ws[WS_OH0 + k] = acc;
            else        ws[WS_EOH1 + k] = expf(acc);
        }
        __syncthreads();
    }
}

// Transposed dataflow (verified R3-R7): C1 = W1·A1^T, C2 = W2·A2^T; inter-layer
// C->B-operand transform via lane^32 shuffle exchange; LDS reads in the chunk
// loop laundered through an opaque zero offset (blocks LICM register-caching,
// the R4/R5 spill cause). R8: pipeline moved bf16 -> f16: layer-1 fragments
// built with v_pk_fma_f16/v_pk_max_f16 on pre-packed (w0,b0) pairs, packs via
// single-inst v_cvt_pkrtz_f16_f32. ks=7 octant structurally zero and skipped.
__global__ __launch_bounds__(256)
void mono_mfma(const float* __restrict__ xsrc,
               const float* __restrict__ iW0, const float* __restrict__ ib0,
               const float* __restrict__ iW1, const float* __restrict__ ib1,
               const float* __restrict__ iW2, const float* __restrict__ ib2,
               const float* __restrict__ iW3, const float* __restrict__ ib3,
               const float* __restrict__ ws,
               float* __restrict__ dst0, float* __restrict__ dst1,
               int kbase, int nTot)
{
    __shared__ __align__(16) _Float16 W1s[DH * WSTR];  // row n1<100, col kin<120; col 100 = b1
    __shared__ __align__(16) _Float16 W2s[DH * WSTR];  // row n2<100, col n1<120;  col 100 = b2
    __shared__ unsigned int w0p_s[64];    // f16 pairs of w0: pair j = slots {2j,2j+1}; 0 past DH
    __shared__ unsigned int b0p_s[64];    // f16 pairs of b0; slot 100 = 1.0
    __shared__ unsigned int w3p_s[64];    // packed bf16 w3 pairs, [hf][nt2][q][pr]; 0 for n2>=100
    __shared__ float xsc_s[128], ccw_s[128];
    __shared__ float xs_s[32], zs[32];

    const int tid = threadIdx.x;
    const int lane = tid & 63;
    const int wv = tid >> 6;
    const int hf = lane >> 5;
    const bool hfb = (hf != 0);
    const int l31 = lane & 31;
    const int k = kbase + blockIdx.y;
    float* __restrict__ dst = (blockIdx.y == 0) ? dst0 : dst1;

    const float* W1g = iW1 + (size_t)k * DH * DH;
    const float* W2g = iW2 + (size_t)k * DH * DH;

    if (tid < 128) {
        xsc_s[tid] = ws[WS_XSC + tid];
        ccw_s[tid] = ws[WS_CCW + tid];
    }
    if (tid < 64) {
        int s0 = 2 * tid, s1 = 2 * tid + 1;
        float w0a = (s0 < DH) ? iW0[(k * DH + s0) * 3] : 0.f;   // h==0: feature 0 only
        float w0b = (s1 < DH) ? iW0[(k * DH + s1) * 3] : 0.f;
        float b0a = (s0 < DH) ? ib0[k * DH + s0] : ((s0 == DH) ? 1.f : 0.f);
        float b0b = (s1 < DH) ? ib0[k * DH + s1] : 0.f;
        w0p_s[tid] = hpk(w0a, w0b);
        b0p_s[tid] = hpk(b0a, b0b);

        int hf_i = tid >> 5, rem = tid & 31;
        int nt2 = rem >> 3, qq = (rem >> 1) & 3, pr = rem & 1;
        int n2e = 32 * nt2 + 8 * qq + 2 * pr + 4 * hf_i;
        float we = (n2e < DH) ? iW3[k * DH + n2e] : 0.f;
        float wo = (n2e + 1 < DH) ? iW3[k * DH + n2e + 1] : 0.f;
        w3p_s[tid] = ((unsigned int)f2bf(wo) << 16) | (unsigned int)f2bf(we);
    }
    if (tid < 32) {
        int n = blockIdx.x * SPB + tid;
        xs_s[tid] = (tid < SPB && n < nTot) ? xsrc[n] : 0.f;
        zs[tid] = 0.f;
    }
    // stage W1/W2 (100 rows x 120 cols; col 100 = bias, 101..119 = 0)
    for (int i = tid; i < DH * WSTR; i += 256) {
        int r = i / WSTR, c = i - r * WSTR;
        float v1, v2;
        if (c < DH)       { v1 = W1g[r * DH + c]; v2 = W2g[r * DH + c]; }
        else if (c == DH) { v1 = ib1[k * DH + r]; v2 = ib2[k * DH + r]; }
        else              { v1 = 0.f; v2 = 0.f; }
        W1s[r * WSTR + c] = (_Float16)v1;
        W2s[r * WSTR + c] = (_Float16)v2;
    }
    __syncthreads();

    const float b3 = ib3[k];
    const float e1 = ws[WS_EOH1 + k];
    const float o0 = ws[WS_OH0 + k];

    // w3 as fp32 registers
    float w3f[64];
    #pragma unroll
    for (int j = 0; j < 32; ++j) {
        unsigned int wu = w3p_s[hf * 32 + j];
        w3f[2 * j]     = __uint_as_float(wu << 16);
        w3f[2 * j + 1] = __uint_as_float(wu & 0xFFFF0000u);
    }

    // per-lane weight-fragment LDS base offsets (row clamped to 99)
    int wrow[4];
    #pragma unroll
    for (int nt = 0; nt < 4; ++nt) {
        int r = nt * 32 + l31;
        wrow[nt] = ((r > DH - 1) ? (DH - 1) : r) * WSTR + hf * 8;
    }

    union FR { f16x8 v; h2 h[4]; unsigned int u32[4]; };

    #pragma unroll 1
    for (int ch = 0; ch < NCH; ++ch) {
        // Opaque zero: every LDS read below depends on it -> LICM blocked.
        unsigned int zoff = 0;
        asm volatile("" : "+v"(zoff));

        const int mrow = ch * 128 + wv * 32 + l31;
        const int nloc = (mrow * 649) >> 16;   // mrow / 101
        const int p = mrow - nloc * 101;
        const float u = xs_s[nloc] * xsc_s[p];
        const h2 uu = hpk2(u, u);

        // ---- layer 1: B-frags ks=0..6 via packed f16 math (bias in slot 100) ----
        FR a1[7];
        #pragma unroll
        for (int ks = 0; ks < 7; ++ks) {
            int pb = ks * 8 + hf * 4 + zoff;          // pair base
            uint4 wq = *(const uint4*)&w0p_s[pb];
            uint4 bq = *(const uint4*)&b0p_s[pb];
            unsigned int wqa[4] = {wq.x, wq.y, wq.z, wq.w};
            unsigned int bqa[4] = {bq.x, bq.y, bq.z, bq.w};
            #pragma unroll
            for (int i = 0; i < 4; ++i) {
                union { unsigned int u; h2 h; } cw, cb;
                cw.u = wqa[i]; cb.u = bqa[i];
                h2 r = __builtin_elementwise_fma(uu, cw.h, cb.h);
                h2 z = {(_Float16)0.f, (_Float16)0.f};
                a1[ks].h[i] = __builtin_elementwise_max(r, z);
            }
        }

        // ---- layer 2: nt-outer, one 16-reg accumulator; pack+exchange -> f3 ----
        FR f3[7];
        #pragma unroll
        for (int nt = 0; nt < 4; ++nt) {
            f32x16 acc;
            #pragma unroll
            for (int r = 0; r < 16; ++r) acc[r] = 0.f;
            #pragma unroll
            for (int ks = 0; ks < 7; ++ks) {
                f16x8 wA = *(const f16x8*)&W1s[wrow[nt] + ks * 16 + zoff];
                acc = __builtin_amdgcn_mfma_f32_32x32x16_f16(wA, a1[ks].v, acc, 0, 0, 0);
            }
            if (nt < 3) {
                unsigned int pk[4][2];
                #pragma unroll
                for (int qi = 0; qi < 4; ++qi) {
                    float a0 = fmaxf(acc[4 * qi + 0], 0.f);
                    float a1v = fmaxf(acc[4 * qi + 1], 0.f);
                    float a2 = fmaxf(acc[4 * qi + 2], 0.f);
                    float a3 = fmaxf(acc[4 * qi + 3], 0.f);
                    pk[qi][0] = hpk(a0, a1v);
                    pk[qi][1] = hpk(a2, a3);
                }
                #pragma unroll
                for (int kk = 0; kk < 2; ++kk) {
                    unsigned int X0 = hfb ? pk[2 * kk][0] : pk[2 * kk + 1][0];
                    unsigned int X1 = hfb ? pk[2 * kk][1] : pk[2 * kk + 1][1];
                    unsigned int O0 = hfb ? pk[2 * kk + 1][0] : pk[2 * kk][0];
                    unsigned int O1 = hfb ? pk[2 * kk + 1][1] : pk[2 * kk][1];
                    unsigned int Y0 = (unsigned int)__shfl_xor((int)X0, 32, 64);
                    unsigned int Y1 = (unsigned int)__shfl_xor((int)X1, 32, 64);
                    f3[nt * 2 + kk].u32[0] = hfb ? Y0 : O0;
                    f3[nt * 2 + kk].u32[1] = hfb ? Y1 : O1;
                    f3[nt * 2 + kk].u32[2] = hfb ? O0 : Y0;
                    f3[nt * 2 + kk].u32[3] = hfb ? O1 : Y1;
                }
            } else {
                // nt=3 tile: only rows 96..99 real; only hf0 readers consume.
                //   hf0: u32[0..1] = rows 96..99, u32[2] = f16 1.0 at k=100,
                //        u32[3] = 0;   hf1 (k=104..111): all zero.
                float a0 = fmaxf(acc[0], 0.f);
                float a1v = fmaxf(acc[1], 0.f);
                float a2 = fmaxf(acc[2], 0.f);
                float a3 = fmaxf(acc[3], 0.f);
                unsigned int p0 = hpk(a0, a1v);
                unsigned int p1 = hpk(a2, a3);
                f3[6].u32[0] = hfb ? 0u : p0;
                f3[6].u32[1] = hfb ? 0u : p1;
                f3[6].u32[2] = hfb ? 0u : 0x00003C00u;   // f16 1.0
                f3[6].u32[3] = 0u;
            }
        }

        // ---- layer 3: nt2-outer, one accumulator; fold w3 (fp32) ----
        float oacc = 0.f;
        #pragma unroll
        for (int nt2 = 0; nt2 < 4; ++nt2) {
            f32x16 acc2;
            #pragma unroll
            for (int r = 0; r < 16; ++r) acc2[r] = 0.f;
            #pragma unroll
            for (int ks = 0; ks < 7; ++ks) {
                f16x8 wA = *(const f16x8*)&W2s[wrow[nt2] + ks * 16 + zoff];
                acc2 = __builtin_amdgcn_mfma_f32_32x32x16_f16(wA, f3[ks].v, acc2, 0, 0, 0);
            }
            #pragma unroll
            for (int r = 0; r < 16; ++r) {
                int qi = r >> 2, s = r & 3;
                float w3v = w3f[2 * (nt2 * 8 + qi * 2 + (s >> 1)) + (s & 1)];
                oacc = fmaf(fmaxf(acc2[r], 0.f), w3v, oacc);
            }
        }

        float o = oacc + __shfl_xor(oacc, 32, 64) + b3;
        float dz = (o > 0.f) ? (o + 1.f) : expf(o);   // elu(o) + 1
        float val = dz * ccw_s[p];
        int nA = __shfl(nloc, 0, 32);
        int nB = __shfl(nloc, 31, 32);
        float vA = (nloc == nA) ? val : 0.f;
        vA += __shfl_xor(vA, 16, 32);
        vA += __shfl_xor(vA, 8, 32);
        vA += __shfl_xor(vA, 4, 32);
        vA += __shfl_xor(vA, 2, 32);
        vA += __shfl_xor(vA, 1, 32);
        if (lane == 0) atomicAdd(&zs[nA], vA);
        if (nB != nA) {
            float vB = (nloc == nB) ? val : 0.f;
            vB += __shfl_xor(vB, 16, 32);
            vB += __shfl_xor(vB, 8, 32);
            vB += __shfl_xor(vB, 4, 32);
            vB += __shfl_xor(vB, 2, 32);
            vB += __shfl_xor(vB, 1, 32);
            if (lane == 1) atomicAdd(&zs[nB], vB);
        }
    }

    __syncthreads();
    if (tid < SPB) {
        int n = blockIdx.x * SPB + tid;
        if (n < nTot) dst[n] = fmaf(e1, 0.5f * xs_s[tid] * zs[tid], o0);
    }
}

extern "C" void kernel_launch(void* const* d_in, const int* in_sizes, int n_in,
                              void* d_out, int out_size, void* d_ws, size_t ws_size,
                              hipStream_t stream)
{
    const float* logits = (const float*)d_in[0];
    const float* iW0 = (const float*)d_in[2];
    const float* ib0 = (const float*)d_in[3];
    const float* iW1 = (const float*)d_in[4];
    const float* ib1 = (const float*)d_in[5];
    const float* iW2 = (const float*)d_in[6];
    const float* ib2 = (const float*)d_in[7];
    const float* iW3 = (const float*)d_in[8];
    const float* ib3 = (const float*)d_in[9];
    const float* hb0 = (const float*)d_in[11];
    const float* hW1 = (const float*)d_in[12];
    const float* hb1 = (const float*)d_in[13];
    const float* hW2 = (const float*)d_in[14];
    const float* hb2 = (const float*)d_in[15];
    const float* hW3 = (const float*)d_in[16];
    const float* hb3 = (const float*)d_in[17];
    float* out = (float*)d_out;
    float* ws = (float*)d_ws;
    int n = in_sizes[0];
    int nblocks = (n + SPB - 1) / SPB;

    hipLaunchKernelGGL(setup_kernel, dim3(64), dim3(256), 0, stream,
                       logits, hb0, hW1, hb1, hW2, hb2, hW3, hb3, ws, out + 2 * n, n);
    // phase A: k=0 -> x2 (workspace), k=1 -> y1
    hipLaunchKernelGGL(mono_mfma, dim3(nblocks, 2), dim3(256), 0, stream,
                       logits, iW0, ib0, iW1, ib1, iW2, ib2, iW3, ib3, ws,
                       ws + WS_X2, out, 0, n);
    // phase B: k=2 on x2 -> y2
    hipLaunchKernelGGL(mono_mfma, dim3(nblocks, 1), dim3(256), 0, stream,
                       ws + WS_X2, iW0, ib0, iW1, ib1, iW2, ib2, iW3, ib3, ws,
                       out + n, out + n, 2, n);
}

// Round 10
// 519.638 us; speedup vs baseline: 2.8072x; 1.0215x over previous
//
#include <hip/hip_runtime.h>
#include <hip/hip_bf16.h>
#include <hip/hip_fp16.h>
#include <math.h>

typedef _Float16 f16x8 __attribute__((ext_vector_type(8)));
typedef _Float16 h2 __attribute__((ext_vector_type(2)));
typedef __fp16 h2amd __attribute__((ext_vector_type(2)));   // builtin return type
typedef float f32x16 __attribute__((ext_vector_type(16)));
typedef float f32x2 __attribute__((ext_vector_type(2)));

#define DH 100      // hidden dim
#define SPB 40      // samples per block -> 4040 rows, padded to 4096
#define NCH 16      // chunks of 256 rows (8 waves x 32)
#define WSTR 120    // LDS row stride in f16 elems (240 B, 16B-aligned; cols 0..119)

// ws float offsets
#define WS_CCW   0
#define WS_XSC   128
#define WS_OH0   256
#define WS_EOH1  260
#define WS_X2    272

__device__ __forceinline__ unsigned short f2bf(float f) {
    unsigned int u = __float_as_uint(f);
    unsigned int r = (u + 0x7FFFu + ((u >> 16) & 1u)) >> 16;  // RNE
    return (unsigned short)r;
}
__device__ __forceinline__ unsigned int hpk(float a, float b) {
    // v_cvt_pkrtz_f16_f32: low u16 = f16(a), high = f16(b)
    union { h2amd h; unsigned int u; } c;
    c.h = __builtin_amdgcn_cvt_pkrtz(a, b);
    return c.u;
}
__device__ __forceinline__ h2 hpk2(float a, float b) {
    union { h2amd ha; h2 h; } c;
    c.ha = __builtin_amdgcn_cvt_pkrtz(a, b);
    return c.h;
}

__global__ void setup_kernel(const float* __restrict__ logits,
                             const float* __restrict__ hb0,
                             const float* __restrict__ hW1,
                             const float* __restrict__ hb1,
                             const float* __restrict__ hW2,
                             const float* __restrict__ hb2,
                             const float* __restrict__ hW3,
                             const float* __restrict__ hb3,
                             float* __restrict__ ws,
                             float* __restrict__ out2, int n)
{
    int t = threadIdx.x;
    for (int i = blockIdx.x * blockDim.x + t; i < n; i += gridDim.x * blockDim.x)
        out2[i] = logits[i];
    if (blockIdx.x != 0) return;

    if (t < 128) {
        double ccw = 0.0, xs = 0.0;
        if (t <= 100) {
            double s = (double)t;
            for (int j = 0; j <= 100; j += 2) {
                double wj = (j == 0) ? 1.0 : 2.0 / (1.0 - (double)j * (double)j);
                double lam;
                if (t == 0) lam = 0.5;
                else {
                    lam = cos((double)j * s * M_PI / 100.0);
                    if (t == 100) lam *= 0.5;
                }
                ccw += lam * 0.02 * wj;
            }
            xs = (cos(s * M_PI / 100.0) + 1.0) * 0.5;
        }
        ws[WS_CCW + t] = (float)ccw;
        ws[WS_XSC + t] = (float)xs;
    }
    __syncthreads();

    __shared__ float bufA[DH], bufB[DH];
    for (int k = 0; k < 3; ++k) {
        if (t < DH) bufA[t] = fmaxf(hb0[k * DH + t], 0.f);
        __syncthreads();
        if (t < DH) {
            float acc = hb1[k * DH + t];
            const float* w = hW1 + (size_t)(k * DH + t) * DH;
            for (int i = 0; i < DH; ++i) acc = fmaf(w[i], bufA[i], acc);
            bufB[t] = fmaxf(acc, 0.f);
        }
        __syncthreads();
        if (t < DH) {
            float acc = hb2[k * DH + t];
            const float* w = hW2 + (size_t)(k * DH + t) * DH;
            for (int i = 0; i < DH; ++i) acc = fmaf(w[i], bufB[i], acc);
            bufA[t] = fmaxf(acc, 0.f);
        }
        __syncthreads();
        if (t < 2) {
            float acc = hb3[k * 2 + t];
            const float* w = hW3 + (size_t)(k * 2 + t) * DH;
            for (int i = 0; i < DH; ++i) acc = fmaf(w[i], bufA[i], acc);
            if (t == 0) ws[WS_OH0 + k] = acc;
            else        ws[WS_EOH1 + k] = expf(acc);
        }
        __syncthreads();
    }
}

// Transposed dataflow (verified R3-R9): C1 = W1·A1^T, C2 = W2·A2^T; inter-layer
// C->B transform via lane^32 shuffle exchange; chunk-loop LDS reads laundered
// through an opaque zero offset (blocks LICM register caching = R4/R5 spill).
// R10: 512-thread blocks (8 waves share one weight-LDS copy -> 16 waves/CU)
// and packed-f32 (v_pk_max/v_pk_fma) in the pack + w3 epilogue.
__global__ __launch_bounds__(512)
void mono_mfma(const float* __restrict__ xsrc,
               const float* __restrict__ iW0, const float* __restrict__ ib0,
               const float* __restrict__ iW1, const float* __restrict__ ib1,
               const float* __restrict__ iW2, const float* __restrict__ ib2,
               const float* __restrict__ iW3, const float* __restrict__ ib3,
               const float* __restrict__ ws,
               float* __restrict__ dst0, float* __restrict__ dst1,
               int kbase, int nTot)
{
    __shared__ __align__(16) _Float16 W1s[DH * WSTR];  // row n1<100, col kin<120; col 100 = b1
    __shared__ __align__(16) _Float16 W2s[DH * WSTR];  // row n2<100, col n1<120;  col 100 = b2
    __shared__ unsigned int w0p_s[64];    // f16 pairs of w0: pair j = slots {2j,2j+1}; 0 past DH
    __shared__ unsigned int b0p_s[64];    // f16 pairs of b0; slot 100 = 1.0
    __shared__ unsigned int w3p_s[64];    // packed bf16 w3 pairs, [hf][nt2][q][pr]; 0 for n2>=100
    __shared__ float xsc_s[128], ccw_s[128];
    __shared__ float xs_s[64], zs[64];

    const int tid = threadIdx.x;
    const int lane = tid & 63;
    const int wv = tid >> 6;            // 0..7
    const int hf = lane >> 5;
    const bool hfb = (hf != 0);
    const int l31 = lane & 31;
    const int k = kbase + blockIdx.y;
    float* __restrict__ dst = (blockIdx.y == 0) ? dst0 : dst1;

    const float* W1g = iW1 + (size_t)k * DH * DH;
    const float* W2g = iW2 + (size_t)k * DH * DH;

    if (tid < 128) {
        xsc_s[tid] = ws[WS_XSC + tid];
        ccw_s[tid] = ws[WS_CCW + tid];
    }
    if (tid < 64) {
        int s0 = 2 * tid, s1 = 2 * tid + 1;
        float w0a = (s0 < DH) ? iW0[(k * DH + s0) * 3] : 0.f;   // h==0: feature 0 only
        float w0b = (s1 < DH) ? iW0[(k * DH + s1) * 3] : 0.f;
        float b0a = (s0 < DH) ? ib0[k * DH + s0] : ((s0 == DH) ? 1.f : 0.f);
        float b0b = (s1 < DH) ? ib0[k * DH + s1] : 0.f;
        w0p_s[tid] = hpk(w0a, w0b);
        b0p_s[tid] = hpk(b0a, b0b);

        int hf_i = tid >> 5, rem = tid & 31;
        int nt2 = rem >> 3, qq = (rem >> 1) & 3, pr = rem & 1;
        int n2e = 32 * nt2 + 8 * qq + 2 * pr + 4 * hf_i;
        float we = (n2e < DH) ? iW3[k * DH + n2e] : 0.f;
        float wo = (n2e + 1 < DH) ? iW3[k * DH + n2e + 1] : 0.f;
        w3p_s[tid] = ((unsigned int)f2bf(wo) << 16) | (unsigned int)f2bf(we);

        int n = blockIdx.x * SPB + tid;
        xs_s[tid] = (tid < SPB && n < nTot) ? xsrc[n] : 0.f;
        zs[tid] = 0.f;
    }
    // stage W1/W2 (100 rows x 120 cols; col 100 = bias, 101..119 = 0)
    for (int i = tid; i < DH * WSTR; i += 512) {
        int r = i / WSTR, c = i - r * WSTR;
        float v1, v2;
        if (c < DH)       { v1 = W1g[r * DH + c]; v2 = W2g[r * DH + c]; }
        else if (c == DH) { v1 = ib1[k * DH + r]; v2 = ib2[k * DH + r]; }
        else              { v1 = 0.f; v2 = 0.f; }
        W1s[r * WSTR + c] = (_Float16)v1;
        W2s[r * WSTR + c] = (_Float16)v2;
    }
    __syncthreads();

    const float b3 = ib3[k];
    const float e1 = ws[WS_EOH1 + k];
    const float o0 = ws[WS_OH0 + k];

    // w3 as fp32 pairs (compiler may remat from LDS; epilogue-only)
    f32x2 w3f2[32];
    #pragma unroll
    for (int j = 0; j < 32; ++j) {
        unsigned int wu = w3p_s[hf * 32 + j];
        w3f2[j][0] = __uint_as_float(wu << 16);
        w3f2[j][1] = __uint_as_float(wu & 0xFFFF0000u);
    }

    // per-lane weight-fragment LDS base offsets (row clamped to 99)
    int wrow[4];
    #pragma unroll
    for (int nt = 0; nt < 4; ++nt) {
        int r = nt * 32 + l31;
        wrow[nt] = ((r > DH - 1) ? (DH - 1) : r) * WSTR + hf * 8;
    }

    union FR { f16x8 v; h2 h[4]; unsigned int u32[4]; };
    const f32x2 zero2 = {0.f, 0.f};

    #pragma unroll 1
    for (int ch = 0; ch < NCH; ++ch) {
        // Opaque zero: every LDS read below depends on it -> LICM blocked.
        unsigned int zoff = 0;
        asm volatile("" : "+v"(zoff));

        const int mrow = ch * 256 + wv * 32 + l31;
        const int nloc = (mrow * 649) >> 16;   // mrow / 101 (exact for mrow < 4096)
        const int p = mrow - nloc * 101;
        const float u = xs_s[nloc] * xsc_s[p];
        const h2 uu = hpk2(u, u);

        // ---- layer 1: B-frags ks=0..6 via packed f16 math (bias in slot 100) ----
        FR a1[7];
        #pragma unroll
        for (int ks = 0; ks < 7; ++ks) {
            int pb = ks * 8 + hf * 4 + zoff;          // pair base
            uint4 wq = *(const uint4*)&w0p_s[pb];
            uint4 bq = *(const uint4*)&b0p_s[pb];
            unsigned int wqa[4] = {wq.x, wq.y, wq.z, wq.w};
            unsigned int bqa[4] = {bq.x, bq.y, bq.z, bq.w};
            #pragma unroll
            for (int i = 0; i < 4; ++i) {
                union { unsigned int u; h2 h; } cw, cb;
                cw.u = wqa[i]; cb.u = bqa[i];
                h2 r = __builtin_elementwise_fma(uu, cw.h, cb.h);
                h2 z = {(_Float16)0.f, (_Float16)0.f};
                a1[ks].h[i] = __builtin_elementwise_max(r, z);
            }
        }

        // ---- layer 2: nt-outer, one 16-reg accumulator; pack+exchange -> f3 ----
        FR f3[7];
        #pragma unroll
        for (int nt = 0; nt < 4; ++nt) {
            f32x16 acc;
            #pragma unroll
            for (int r = 0; r < 16; ++r) acc[r] = 0.f;
            #pragma unroll
            for (int ks = 0; ks < 7; ++ks) {
                f16x8 wA = *(const f16x8*)&W1s[wrow[nt] + ks * 16 + zoff];
                acc = __builtin_amdgcn_mfma_f32_32x32x16_f16(wA, a1[ks].v, acc, 0, 0, 0);
            }
            if (nt < 3) {
                unsigned int pk[4][2];
                #pragma unroll
                for (int qi = 0; qi < 4; ++qi) {
                    f32x2 lo = {acc[4 * qi + 0], acc[4 * qi + 1]};
                    f32x2 hi = {acc[4 * qi + 2], acc[4 * qi + 3]};
                    lo = __builtin_elementwise_max(lo, zero2);   // v_pk_max_f32
                    hi = __builtin_elementwise_max(hi, zero2);
                    pk[qi][0] = hpk(lo[0], lo[1]);
                    pk[qi][1] = hpk(hi[0], hi[1]);
                }
                #pragma unroll
                for (int kk = 0; kk < 2; ++kk) {
                    unsigned int X0 = hfb ? pk[2 * kk][0] : pk[2 * kk + 1][0];
                    unsigned int X1 = hfb ? pk[2 * kk][1] : pk[2 * kk + 1][1];
                    unsigned int O0 = hfb ? pk[2 * kk + 1][0] : pk[2 * kk][0];
                    unsigned int O1 = hfb ? pk[2 * kk + 1][1] : pk[2 * kk][1];
                    unsigned int Y0 = (unsigned int)__shfl_xor((int)X0, 32, 64);
                    unsigned int Y1 = (unsigned int)__shfl_xor((int)X1, 32, 64);
                    f3[nt * 2 + kk].u32[0] = hfb ? Y0 : O0;
                    f3[nt * 2 + kk].u32[1] = hfb ? Y1 : O1;
                    f3[nt * 2 + kk].u32[2] = hfb ? O0 : Y0;
                    f3[nt * 2 + kk].u32[3] = hfb ? O1 : Y1;
                }
            } else {
                // nt=3 tile: only rows 96..99 real; only hf0 readers consume.
                //   hf0: u32[0..1] = rows 96..99, u32[2] = f16 1.0 at k=100,
                //        u32[3] = 0;   hf1 (k=104..111): all zero.
                f32x2 lo = {acc[0], acc[1]};
                f32x2 hi = {acc[2], acc[3]};
                lo = __builtin_elementwise_max(lo, zero2);
                hi = __builtin_elementwise_max(hi, zero2);
                unsigned int p0 = hpk(lo[0], lo[1]);
                unsigned int p1 = hpk(hi[0], hi[1]);
                f3[6].u32[0] = hfb ? 0u : p0;
                f3[6].u32[1] = hfb ? 0u : p1;
                f3[6].u32[2] = hfb ? 0u : 0x00003C00u;   // f16 1.0
                f3[6].u32[3] = 0u;
            }
        }

        // ---- layer 3: nt2-outer, one accumulator; fold w3 via packed f32 ----
        f32x2 oacc2 = {0.f, 0.f};
        #pragma unroll
        for (int nt2 = 0; nt2 < 4; ++nt2) {
            f32x16 acc2;
            #pragma unroll
            for (int r = 0; r < 16; ++r) acc2[r] = 0.f;
            #pragma unroll
            for (int ks = 0; ks < 7; ++ks) {
                f16x8 wA = *(const f16x8*)&W2s[wrow[nt2] + ks * 16 + zoff];
                acc2 = __builtin_amdgcn_mfma_f32_32x32x16_f16(wA, f3[ks].v, acc2, 0, 0, 0);
            }
            #pragma unroll
            for (int qi = 0; qi < 4; ++qi) {
                f32x2 lo = {acc2[4 * qi + 0], acc2[4 * qi + 1]};
                f32x2 hi = {acc2[4 * qi + 2], acc2[4 * qi + 3]};
                lo = __builtin_elementwise_max(lo, zero2);          // v_pk_max_f32
                hi = __builtin_elementwise_max(hi, zero2);
                oacc2 = __builtin_elementwise_fma(lo, w3f2[nt2 * 8 + qi * 2], oacc2);      // v_pk_fma_f32
                oacc2 = __builtin_elementwise_fma(hi, w3f2[nt2 * 8 + qi * 2 + 1], oacc2);
            }
        }
        float oacc = oacc2[0] + oacc2[1];

        float o = oacc + __shfl_xor(oacc, 32, 64) + b3;
        float dz = (o > 0.f) ? (o + 1.f) : expf(o);   // elu(o) + 1
        float val = dz * ccw_s[p];
        int nA = __shfl(nloc, 0, 32);
        int nB = __shfl(nloc, 31, 32);
        float vA = (nloc == nA) ? val : 0.f;
        vA += __shfl_xor(vA, 16, 32);
        vA += __shfl_xor(vA, 8, 32);
        vA += __shfl_xor(vA, 4, 32);
        vA += __shfl_xor(vA, 2, 32);
        vA += __shfl_xor(vA, 1, 32);
        if (lane == 0) atomicAdd(&zs[nA], vA);
        if (nB != nA) {
            float vB = (nloc == nB) ? val : 0.f;
            vB += __shfl_xor(vB, 16, 32);
            vB += __shfl_xor(vB, 8, 32);
            vB += __shfl_xor(vB, 4, 32);
            vB += __shfl_xor(vB, 2, 32);
            vB += __shfl_xor(vB, 1, 32);
            if (lane == 1) atomicAdd(&zs[nB], vB);
        }
    }

    __syncthreads();
    if (tid < SPB) {
        int n = blockIdx.x * SPB + tid;
        if (n < nTot) dst[n] = fmaf(e1, 0.5f * xs_s[tid] * zs[tid], o0);
    }
}

extern "C" void kernel_launch(void* const* d_in, const int* in_sizes, int n_in,
                              void* d_out, int out_size, void* d_ws, size_t ws_size,
                              hipStream_t stream)
{
    const float* logits = (const float*)d_in[0];
    const float* iW0 = (const float*)d_in[2];
    const float* ib0 = (const float*)d_in[3];
    const float* iW1 = (const float*)d_in[4];
    const float* ib1 = (const float*)d_in[5];
    const float* iW2 = (const float*)d_in[6];
    const float* ib2 = (const float*)d_in[7];
    const float* iW3 = (const float*)d_in[8];
    const float* ib3 = (const float*)d_in[9];
    const float* hb0 = (const float*)d_in[11];
    const float* hW1 = (const float*)d_in[12];
    const float* hb1 = (const float*)d_in[13];
    const float* hW2 = (const float*)d_in[14];
    const float* hb2 = (const float*)d_in[15];
    const float* hW3 = (const float*)d_in[16];
    const float* hb3 = (const float*)d_in[17];
    float* out = (float*)d_out;
    float* ws = (float*)d_ws;
    int n = in_sizes[0];
    int nblocks = (n + SPB - 1) / SPB;

    hipLaunchKernelGGL(setup_kernel, dim3(64), dim3(256), 0, stream,
                       logits, hb0, hW1, hb1, hW2, hb2, hW3, hb3, ws, out + 2 * n, n);
    // phase A: k=0 -> x2 (workspace), k=1 -> y1
    hipLaunchKernelGGL(mono_mfma, dim3(nblocks, 2), dim3(512), 0, stream,
                       logits, iW0, ib0, iW1, ib1, iW2, ib2, iW3, ib3, ws,
                       ws + WS_X2, out, 0, n);
    // phase B: k=2 on x2 -> y2
    hipLaunchKernelGGL(mono_mfma, dim3(nblocks, 1), dim3(512), 0, stream,
                       ws + WS_X2, iW0, ib0, iW1, ib1, iW2, ib2, iW3, ib3, ws,
                       out + n, out + n, 2, n);
}

// Round 11
// 500.431 us; speedup vs baseline: 2.9149x; 1.0384x over previous
//
#include <hip/hip_runtime.h>
#include <hip/hip_bf16.h>
#include <hip/hip_fp16.h>
#include <math.h>

typedef _Float16 f16x8 __attribute__((ext_vector_type(8)));
typedef _Float16 h2 __attribute__((ext_vector_type(2)));
typedef __fp16 h2amd __attribute__((ext_vector_type(2)));   // builtin return type
typedef float f32x16 __attribute__((ext_vector_type(16)));
typedef float f32x2 __attribute__((ext_vector_type(2)));

#define DH 100      // hidden dim
#define SPB 20      // samples per block -> 2020 rows, padded to 2048
#define NIT 8       // iterations; each processes 2 chunks of 128 rows
#define WSTR 120    // LDS row stride in f16 elems (240 B, 16B-aligned; cols 0..119)

// ws float offsets
#define WS_CCW   0
#define WS_XSC   128
#define WS_OH0   256
#define WS_EOH1  260
#define WS_X2    272

__device__ __forceinline__ unsigned short f2bf(float f) {
    unsigned int u = __float_as_uint(f);
    unsigned int r = (u + 0x7FFFu + ((u >> 16) & 1u)) >> 16;  // RNE
    return (unsigned short)r;
}
__device__ __forceinline__ unsigned int hpk(float a, float b) {
    union { h2amd h; unsigned int u; } c;
    c.h = __builtin_amdgcn_cvt_pkrtz(a, b);
    return c.u;
}
__device__ __forceinline__ h2 hpk2(float a, float b) {
    union { h2amd ha; h2 h; } c;
    c.ha = __builtin_amdgcn_cvt_pkrtz(a, b);
    return c.h;
}

__global__ void setup_kernel(const float* __restrict__ logits,
                             const float* __restrict__ hb0,
                             const float* __restrict__ hW1,
                             const float* __restrict__ hb1,
                             const float* __restrict__ hW2,
                             const float* __restrict__ hb2,
                             const float* __restrict__ hW3,
                             const float* __restrict__ hb3,
                             float* __restrict__ ws,
                             float* __restrict__ out2, int n)
{
    int t = threadIdx.x;
    for (int i = blockIdx.x * blockDim.x + t; i < n; i += gridDim.x * blockDim.x)
        out2[i] = logits[i];
    if (blockIdx.x != 0) return;

    if (t < 128) {
        double ccw = 0.0, xs = 0.0;
        if (t <= 100) {
            double s = (double)t;
            for (int j = 0; j <= 100; j += 2) {
                double wj = (j == 0) ? 1.0 : 2.0 / (1.0 - (double)j * (double)j);
                double lam;
                if (t == 0) lam = 0.5;
                else {
                    lam = cos((double)j * s * M_PI / 100.0);
                    if (t == 100) lam *= 0.5;
                }
                ccw += lam * 0.02 * wj;
            }
            xs = (cos(s * M_PI / 100.0) + 1.0) * 0.5;
        }
        ws[WS_CCW + t] = (float)ccw;
        ws[WS_XSC + t] = (float)xs;
    }
    __syncthreads();

    __shared__ float bufA[DH], bufB[DH];
    for (int k = 0; k < 3; ++k) {
        if (t < DH) bufA[t] = fmaxf(hb0[k * DH + t], 0.f);
        __syncthreads();
        if (t < DH) {
            float acc = hb1[k * DH + t];
            const float* w = hW1 + (size_t)(k * DH + t) * DH;
            for (int i = 0; i < DH; ++i) acc = fmaf(w[i], bufA[i], acc);
            bufB[t] = fmaxf(acc, 0.f);
        }
        __syncthreads();
        if (t < DH) {
            float acc = hb2[k * DH + t];
            const float* w = hW2 + (size_t)(k * DH + t) * DH;
            for (int i = 0; i < DH; ++i) acc = fmaf(w[i], bufB[i], acc);
            bufA[t] = fmaxf(acc, 0.f);
        }
        __syncthreads();
        if (t < 2) {
            float acc = hb3[k * 2 + t];
            const float* w = hW3 + (size_t)(k * 2 + t) * DH;
            for (int i = 0; i < DH; ++i) acc = fmaf(w[i], bufA[i], acc);
            if (t == 0) ws[WS_OH0 + k] = acc;
            else        ws[WS_EOH1 + k] = expf(acc);
        }
        __syncthreads();
    }
}

// Transposed dataflow (verified R3-R10): C1 = W1·A1^T, C2 = W2·A2^T; C->B
// transform via lane^32 shuffle exchange; chunk-loop LDS reads laundered
// through an opaque zero offset (blocks LICM register caching = R4/R5 spill).
// R11: LDS-pipe is the bottleneck (~70 ds_read_b128/chunk-wave vs 56 MFMA) ->
// process TWO chunks per iteration sharing every weight/const LDS read
// (one load feeds two MFMAs): ~45% less LDS traffic + 2 independent MFMA
// chains for latency hiding. 256-thread blocks (512-thr regressed, R10).
__global__ __launch_bounds__(256)
void mono_mfma(const float* __restrict__ xsrc,
               const float* __restrict__ iW0, const float* __restrict__ ib0,
               const float* __restrict__ iW1, const float* __restrict__ ib1,
               const float* __restrict__ iW2, const float* __restrict__ ib2,
               const float* __restrict__ iW3, const float* __restrict__ ib3,
               const float* __restrict__ ws,
               float* __restrict__ dst0, float* __restrict__ dst1,
               int kbase, int nTot)
{
    __shared__ __align__(16) _Float16 W1s[DH * WSTR];  // row n1<100, col kin<120; col 100 = b1
    __shared__ __align__(16) _Float16 W2s[DH * WSTR];  // row n2<100, col n1<120;  col 100 = b2
    __shared__ unsigned int w0p_s[64];    // f16 pairs of w0: pair j = slots {2j,2j+1}; 0 past DH
    __shared__ unsigned int b0p_s[64];    // f16 pairs of b0; slot 100 = 1.0
    __shared__ unsigned int w3p_s[64];    // packed bf16 w3 pairs, [hf][nt2][q][pr]; 0 for n2>=100
    __shared__ float xsc_s[128], ccw_s[128];
    __shared__ float xs_s[32], zs[32];

    const int tid = threadIdx.x;
    const int lane = tid & 63;
    const int wv = tid >> 6;
    const int hf = lane >> 5;
    const bool hfb = (hf != 0);
    const int l31 = lane & 31;
    const int k = kbase + blockIdx.y;
    float* __restrict__ dst = (blockIdx.y == 0) ? dst0 : dst1;

    const float* W1g = iW1 + (size_t)k * DH * DH;
    const float* W2g = iW2 + (size_t)k * DH * DH;

    if (tid < 128) {
        xsc_s[tid] = ws[WS_XSC + tid];
        ccw_s[tid] = ws[WS_CCW + tid];
    }
    if (tid < 64) {
        int s0 = 2 * tid, s1 = 2 * tid + 1;
        float w0a = (s0 < DH) ? iW0[(k * DH + s0) * 3] : 0.f;   // h==0: feature 0 only
        float w0b = (s1 < DH) ? iW0[(k * DH + s1) * 3] : 0.f;
        float b0a = (s0 < DH) ? ib0[k * DH + s0] : ((s0 == DH) ? 1.f : 0.f);
        float b0b = (s1 < DH) ? ib0[k * DH + s1] : 0.f;
        w0p_s[tid] = hpk(w0a, w0b);
        b0p_s[tid] = hpk(b0a, b0b);

        int hf_i = tid >> 5, rem = tid & 31;
        int nt2 = rem >> 3, qq = (rem >> 1) & 3, pr = rem & 1;
        int n2e = 32 * nt2 + 8 * qq + 2 * pr + 4 * hf_i;
        float we = (n2e < DH) ? iW3[k * DH + n2e] : 0.f;
        float wo = (n2e + 1 < DH) ? iW3[k * DH + n2e + 1] : 0.f;
        w3p_s[tid] = ((unsigned int)f2bf(wo) << 16) | (unsigned int)f2bf(we);
    }
    if (tid < 32) {
        int n = blockIdx.x * SPB + tid;
        xs_s[tid] = (tid < SPB && n < nTot) ? xsrc[n] : 0.f;
        zs[tid] = 0.f;
    }
    // stage W1/W2 (100 rows x 120 cols; col 100 = bias, 101..119 = 0)
    for (int i = tid; i < DH * WSTR; i += 256) {
        int r = i / WSTR, c = i - r * WSTR;
        float v1, v2;
        if (c < DH)       { v1 = W1g[r * DH + c]; v2 = W2g[r * DH + c]; }
        else if (c == DH) { v1 = ib1[k * DH + r]; v2 = ib2[k * DH + r]; }
        else              { v1 = 0.f; v2 = 0.f; }
        W1s[r * WSTR + c] = (_Float16)v1;
        W2s[r * WSTR + c] = (_Float16)v2;
    }
    __syncthreads();

    const float b3 = ib3[k];
    const float e1 = ws[WS_EOH1 + k];
    const float o0 = ws[WS_OH0 + k];

    // per-lane weight-fragment LDS base offsets (row clamped to 99)
    int wrow[4];
    #pragma unroll
    for (int nt = 0; nt < 4; ++nt) {
        int r = nt * 32 + l31;
        wrow[nt] = ((r > DH - 1) ? (DH - 1) : r) * WSTR + hf * 8;
    }

    union FR { f16x8 v; h2 h[4]; unsigned int u32[4]; };
    const f32x2 zero2 = {0.f, 0.f};

    #pragma unroll 1
    for (int it = 0; it < NIT; ++it) {
        // Opaque zero: every LDS read below depends on it -> LICM blocked.
        unsigned int zoff = 0;
        asm volatile("" : "+v"(zoff));

        int nloc[2], p[2];
        h2 uu[2];
        #pragma unroll
        for (int j = 0; j < 2; ++j) {
            int mrow = it * 256 + j * 128 + wv * 32 + l31;
            nloc[j] = (mrow * 649) >> 16;   // mrow / 101 (exact for mrow < 2048)
            p[j] = mrow - nloc[j] * 101;
            float u = xs_s[nloc[j]] * xsc_s[p[j]];
            uu[j] = hpk2(u, u);
        }

        // ---- layer 1: B-frags for BOTH chunks, sharing w0/b0 loads ----
        FR a1[2][7];
        #pragma unroll
        for (int ks = 0; ks < 7; ++ks) {
            int pb = ks * 8 + hf * 4 + zoff;          // pair base
            uint4 wq = *(const uint4*)&w0p_s[pb];
            uint4 bq = *(const uint4*)&b0p_s[pb];
            unsigned int wqa[4] = {wq.x, wq.y, wq.z, wq.w};
            unsigned int bqa[4] = {bq.x, bq.y, bq.z, bq.w};
            #pragma unroll
            for (int i = 0; i < 4; ++i) {
                union { unsigned int u; h2 h; } cw, cb;
                cw.u = wqa[i]; cb.u = bqa[i];
                h2 z = {(_Float16)0.f, (_Float16)0.f};
                #pragma unroll
                for (int j = 0; j < 2; ++j) {
                    h2 r = __builtin_elementwise_fma(uu[j], cw.h, cb.h);
                    a1[j][ks].h[i] = __builtin_elementwise_max(r, z);
                }
            }
        }

        // ---- layer 2: nt-outer, dual accumulators sharing weight loads ----
        FR f3[2][7];
        #pragma unroll
        for (int nt = 0; nt < 4; ++nt) {
            f32x16 acc[2];
            #pragma unroll
            for (int r = 0; r < 16; ++r) { acc[0][r] = 0.f; acc[1][r] = 0.f; }
            #pragma unroll
            for (int ks = 0; ks < 7; ++ks) {
                f16x8 wA = *(const f16x8*)&W1s[wrow[nt] + ks * 16 + zoff];
                acc[0] = __builtin_amdgcn_mfma_f32_32x32x16_f16(wA, a1[0][ks].v, acc[0], 0, 0, 0);
                acc[1] = __builtin_amdgcn_mfma_f32_32x32x16_f16(wA, a1[1][ks].v, acc[1], 0, 0, 0);
            }
            #pragma unroll
            for (int j = 0; j < 2; ++j) {
                if (nt < 3) {
                    unsigned int pk[4][2];
                    #pragma unroll
                    for (int qi = 0; qi < 4; ++qi) {
                        f32x2 lo = {acc[j][4 * qi + 0], acc[j][4 * qi + 1]};
                        f32x2 hi = {acc[j][4 * qi + 2], acc[j][4 * qi + 3]};
                        lo = __builtin_elementwise_max(lo, zero2);   // v_pk_max_f32
                        hi = __builtin_elementwise_max(hi, zero2);
                        pk[qi][0] = hpk(lo[0], lo[1]);
                        pk[qi][1] = hpk(hi[0], hi[1]);
                    }
                    #pragma unroll
                    for (int kk = 0; kk < 2; ++kk) {
                        unsigned int X0 = hfb ? pk[2 * kk][0] : pk[2 * kk + 1][0];
                        unsigned int X1 = hfb ? pk[2 * kk][1] : pk[2 * kk + 1][1];
                        unsigned int O0 = hfb ? pk[2 * kk + 1][0] : pk[2 * kk][0];
                        unsigned int O1 = hfb ? pk[2 * kk + 1][1] : pk[2 * kk][1];
                        unsigned int Y0 = (unsigned int)__shfl_xor((int)X0, 32, 64);
                        unsigned int Y1 = (unsigned int)__shfl_xor((int)X1, 32, 64);
                        f3[j][nt * 2 + kk].u32[0] = hfb ? Y0 : O0;
                        f3[j][nt * 2 + kk].u32[1] = hfb ? Y1 : O1;
                        f3[j][nt * 2 + kk].u32[2] = hfb ? O0 : Y0;
                        f3[j][nt * 2 + kk].u32[3] = hfb ? O1 : Y1;
                    }
                } else {
                    // nt=3 tile: only rows 96..99 real; only hf0 readers consume.
                    f32x2 lo = {acc[j][0], acc[j][1]};
                    f32x2 hi = {acc[j][2], acc[j][3]};
                    lo = __builtin_elementwise_max(lo, zero2);
                    hi = __builtin_elementwise_max(hi, zero2);
                    unsigned int p0 = hpk(lo[0], lo[1]);
                    unsigned int p1 = hpk(hi[0], hi[1]);
                    f3[j][6].u32[0] = hfb ? 0u : p0;
                    f3[j][6].u32[1] = hfb ? 0u : p1;
                    f3[j][6].u32[2] = hfb ? 0u : 0x00003C00u;   // f16 1.0
                    f3[j][6].u32[3] = 0u;
                }
            }
        }

        // ---- layer 3: nt2-outer, dual accumulators; shared W2 + w3 loads ----
        f32x2 oacc2[2] = {{0.f, 0.f}, {0.f, 0.f}};
        #pragma unroll
        for (int nt2 = 0; nt2 < 4; ++nt2) {
            f32x16 acc2[2];
            #pragma unroll
            for (int r = 0; r < 16; ++r) { acc2[0][r] = 0.f; acc2[1][r] = 0.f; }
            #pragma unroll
            for (int ks = 0; ks < 7; ++ks) {
                f16x8 wA = *(const f16x8*)&W2s[wrow[nt2] + ks * 16 + zoff];
                acc2[0] = __builtin_amdgcn_mfma_f32_32x32x16_f16(wA, f3[0][ks].v, acc2[0], 0, 0, 0);
                acc2[1] = __builtin_amdgcn_mfma_f32_32x32x16_f16(wA, f3[1][ks].v, acc2[1], 0, 0, 0);
            }
            uint4 wa = *(const uint4*)&w3p_s[hf * 32 + nt2 * 8 + zoff];
            uint4 wb2 = *(const uint4*)&w3p_s[hf * 32 + nt2 * 8 + 4 + zoff];
            unsigned int w8[8] = {wa.x, wa.y, wa.z, wa.w, wb2.x, wb2.y, wb2.z, wb2.w};
            f32x2 w3v[8];
            #pragma unroll
            for (int q = 0; q < 8; ++q) {
                w3v[q][0] = __uint_as_float(w8[q] << 16);
                w3v[q][1] = __uint_as_float(w8[q] & 0xFFFF0000u);
            }
            #pragma unroll
            for (int j = 0; j < 2; ++j)
                #pragma unroll
                for (int qi = 0; qi < 4; ++qi) {
                    f32x2 lo = {acc2[j][4 * qi + 0], acc2[j][4 * qi + 1]};
                    f32x2 hi = {acc2[j][4 * qi + 2], acc2[j][4 * qi + 3]};
                    lo = __builtin_elementwise_max(lo, zero2);          // v_pk_max_f32
                    hi = __builtin_elementwise_max(hi, zero2);
                    oacc2[j] = __builtin_elementwise_fma(lo, w3v[qi * 2], oacc2[j]);      // v_pk_fma_f32
                    oacc2[j] = __builtin_elementwise_fma(hi, w3v[qi * 2 + 1], oacc2[j]);
                }
        }

        // ---- epilogue x2: elu+1, quadrature weight, segmented reduce ----
        #pragma unroll
        for (int j = 0; j < 2; ++j) {
            float oacc = oacc2[j][0] + oacc2[j][1];
            float o = oacc + __shfl_xor(oacc, 32, 64) + b3;
            float dz = (o > 0.f) ? (o + 1.f) : expf(o);   // elu(o) + 1
            float val = dz * ccw_s[p[j]];
            int nA = __shfl(nloc[j], 0, 32);
            int nB = __shfl(nloc[j], 31, 32);
            float vA = (nloc[j] == nA) ? val : 0.f;
            vA += __shfl_xor(vA, 16, 32);
            vA += __shfl_xor(vA, 8, 32);
            vA += __shfl_xor(vA, 4, 32);
            vA += __shfl_xor(vA, 2, 32);
            vA += __shfl_xor(vA, 1, 32);
            if (lane == 0) atomicAdd(&zs[nA], vA);
            if (nB != nA) {
                float vB = (nloc[j] == nB) ? val : 0.f;
                vB += __shfl_xor(vB, 16, 32);
                vB += __shfl_xor(vB, 8, 32);
                vB += __shfl_xor(vB, 4, 32);
                vB += __shfl_xor(vB, 2, 32);
                vB += __shfl_xor(vB, 1, 32);
                if (lane == 1) atomicAdd(&zs[nB], vB);
            }
        }
    }

    __syncthreads();
    if (tid < SPB) {
        int n = blockIdx.x * SPB + tid;
        if (n < nTot) dst[n] = fmaf(e1, 0.5f * xs_s[tid] * zs[tid], o0);
    }
}

extern "C" void kernel_launch(void* const* d_in, const int* in_sizes, int n_in,
                              void* d_out, int out_size, void* d_ws, size_t ws_size,
                              hipStream_t stream)
{
    const float* logits = (const float*)d_in[0];
    const float* iW0 = (const float*)d_in[2];
    const float* ib0 = (const float*)d_in[3];
    const float* iW1 = (const float*)d_in[4];
    const float* ib1 = (const float*)d_in[5];
    const float* iW2 = (const float*)d_in[6];
    const float* ib2 = (const float*)d_in[7];
    const float* iW3 = (const float*)d_in[8];
    const float* ib3 = (const float*)d_in[9];
    const float* hb0 = (const float*)d_in[11];
    const float* hW1 = (const float*)d_in[12];
    const float* hb1 = (const float*)d_in[13];
    const float* hW2 = (const float*)d_in[14];
    const float* hb2 = (const float*)d_in[15];
    const float* hW3 = (const float*)d_in[16];
    const float* hb3 = (const float*)d_in[17];
    float* out = (float*)d_out;
    float* ws = (float*)d_ws;
    int n = in_sizes[0];
    int nblocks = (n + SPB - 1) / SPB;

    hipLaunchKernelGGL(setup_kernel, dim3(64), dim3(256), 0, stream,
                       logits, hb0, hW1, hb1, hW2, hb2, hW3, hb3, ws, out + 2 * n, n);
    // phase A: k=0 -> x2 (workspace), k=1 -> y1
    hipLaunchKernelGGL(mono_mfma, dim3(nblocks, 2), dim3(256), 0, stream,
                       logits, iW0, ib0, iW1, ib1, iW2, ib2, iW3, ib3, ws,
                       ws + WS_X2, out, 0, n);
    // phase B: k=2 on x2 -> y2
    hipLaunchKernelGGL(mono_mfma, dim3(nblocks, 1), dim3(256), 0, stream,
                       ws + WS_X2, iW0, ib0, iW1, ib1, iW2, ib2, iW3, ib3, ws,
                       out + n, out + n, 2, n);
}